// Round 1
// baseline (1226.094 us; speedup 1.0000x reference)
//
#include <hip/hip_runtime.h>
#include <math.h>

// Problem constants
#define Bn   8
#define Nn   2048
#define Dn   192
#define Gn   512
#define Sn   32
#define OUTn 384
#define Mrows (Bn * Gn * Sn)   // 131072 rows through the MLP

typedef __attribute__((ext_vector_type(8))) unsigned short ushortx8;
typedef __attribute__((ext_vector_type(8))) __bf16 bf16x8;
typedef __attribute__((ext_vector_type(4))) float floatx4;

// ---------- ws layout (bytes) ----------
static constexpr size_t OFF_KNN   = 0;                    // 131072 * 4
static constexpr size_t OFF_CIDX  = 524288;               // 4096 * 4
static constexpr size_t OFF_DIFF  = 540672;               // 393216 * 4
static constexpr size_t OFF_SUMS  = 2113536;              // 2 doubles
static constexpr size_t OFF_STD   = 2113552;              // 1 float
static constexpr size_t OFF_DENOM = 2113792;              // 64 floats
static constexpr size_t OFF_W1B   = 2114048;              // 147456 * 2
static constexpr size_t OFF_WAB   = 2408960;              // 73728 * 2
static constexpr size_t OFF_WBB   = 2556416;              // 73728 * 2
static constexpr size_t OFF_G1    = 2703872;              // 50331648 * 2
static constexpr size_t OFF_H     = 103367168;            // 25165824 * 2
// total ~153.7 MB

__device__ __forceinline__ unsigned short f2bf(float f) {
  unsigned u = __float_as_uint(f);
  unsigned r = (u + 0x7FFFu + ((u >> 16) & 1u)) >> 16;   // RNE
  return (unsigned short)r;
}
__device__ __forceinline__ float bf2f(unsigned short h) {
  return __uint_as_float(((unsigned)h) << 16);
}
__device__ __forceinline__ floatx4 mfma_bf16(ushortx8 a, ushortx8 b, floatx4 c) {
  return __builtin_amdgcn_mfma_f32_16x16x32_bf16(
      __builtin_bit_cast(bf16x8, a), __builtin_bit_cast(bf16x8, b), c, 0, 0, 0);
}

// ---------------------------------------------------------------------------
// prep: fp32 weights -> bf16, and Fourier denom table
// ---------------------------------------------------------------------------
__global__ void prep_kernel(const float* __restrict__ W1, const float* __restrict__ Wa,
                            const float* __restrict__ Wb,
                            unsigned short* __restrict__ W1b, unsigned short* __restrict__ Wab,
                            unsigned short* __restrict__ Wbb, float* __restrict__ denomTab) {
  int i = blockIdx.x * 256 + threadIdx.x;
  if (i < 147456)            W1b[i] = f2bf(W1[i]);
  else if (i < 221184)       Wab[i - 147456] = f2bf(Wa[i - 147456]);
  else if (i < 294912)       Wbb[i - 221184] = f2bf(Wb[i - 221184]);
  if (blockIdx.x == 0 && threadIdx.x < 64)
    denomTab[threadIdx.x] = (float)pow(1000.0, (double)threadIdx.x / 64.0);
}

// ---------------------------------------------------------------------------
// FPS: one block per batch. Exact IEEE fp32 ops (no contraction), first-index
// tie-break to match numpy argmax. Writes centers straight into d_out.
// ---------------------------------------------------------------------------
__global__ __launch_bounds__(256) void fps_kernel(const float* __restrict__ points,
                                                  float* __restrict__ centers) {
  const int b = blockIdx.x;
  const int t = threadIdx.x;
  __shared__ float px[Nn], py[Nn], pz[Nn];
  __shared__ float wv[4];
  __shared__ int   wi[4];
  __shared__ int   curs;

  const float* P = points + (size_t)b * Nn * 3;
  for (int i = t; i < Nn * 3; i += 256) {
    float v = P[i];
    int n = i / 3, c = i - n * 3;
    if (c == 0) px[n] = v; else if (c == 1) py[n] = v; else pz[n] = v;
  }
  __syncthreads();

  float rx[8], ry[8], rz[8], dist[8];
#pragma unroll
  for (int k = 0; k < 8; ++k) {
    int n = t + 256 * k;
    rx[k] = px[n]; ry[k] = py[n]; rz[k] = pz[n];
    dist[k] = INFINITY;
  }

  int cur = 0;
  for (int it = 0; it < Gn; ++it) {
    float cx = px[cur], cy = py[cur], cz = pz[cur];
    if (t == 0) {
      float* cd = centers + ((size_t)b * Gn + it) * 3;
      cd[0] = cx; cd[1] = cy; cd[2] = cz;
    }
    float bv = -1.0f; int bi = 0;
#pragma unroll
    for (int k = 0; k < 8; ++k) {
      float dx = __fsub_rn(rx[k], cx);
      float dy = __fsub_rn(ry[k], cy);
      float dz = __fsub_rn(rz[k], cz);
      float d = __fadd_rn(__fadd_rn(__fmul_rn(dx, dx), __fmul_rn(dy, dy)), __fmul_rn(dz, dz));
      dist[k] = fminf(dist[k], d);
      if (dist[k] > bv) { bv = dist[k]; bi = t + 256 * k; }
    }
#pragma unroll
    for (int off = 32; off >= 1; off >>= 1) {
      float ov = __shfl_xor(bv, off, 64);
      int   oi = __shfl_xor(bi, off, 64);
      if (ov > bv || (ov == bv && oi < bi)) { bv = ov; bi = oi; }
    }
    if ((t & 63) == 0) { wv[t >> 6] = bv; wi[t >> 6] = bi; }
    __syncthreads();
    if (t == 0) {
      float Bv = wv[0]; int Bi = wi[0];
      for (int w = 1; w < 4; ++w)
        if (wv[w] > Bv || (wv[w] == Bv && wi[w] < Bi)) { Bv = wv[w]; Bi = wi[w]; }
      curs = Bi;
    }
    __syncthreads();
    cur = curs;
  }
}

// ---------------------------------------------------------------------------
// KNN: one block per (b,g). Exact d2 = (aa+bb) - 2*dot (np association),
// leader-based exact top-32 extraction (lowest-index tie-break, matches
// lax.top_k / argmin). Also emits diff and fp64 partial sums for global std.
// ---------------------------------------------------------------------------
__global__ __launch_bounds__(256) void knn_kernel(const float* __restrict__ points,
                                                  const float* __restrict__ centers,
                                                  int* __restrict__ knn, int* __restrict__ cidx,
                                                  float* __restrict__ diffb,
                                                  double* __restrict__ sums) {
  const int bg = blockIdx.x;
  const int b = bg >> 9;
  const int t = threadIdx.x;
  __shared__ float px[Nn], py[Nn], pz[Nn];
  __shared__ float d2s[Nn];
  __shared__ float lval[256];
  __shared__ int   lidx[256];
  __shared__ int   sel[Sn];
  __shared__ int   wpos;
  __shared__ float tmp[96];

  const float* P = points + (size_t)b * Nn * 3;
  for (int i = t; i < Nn * 3; i += 256) {
    float v = P[i];
    int n = i / 3, c = i - n * 3;
    if (c == 0) px[n] = v; else if (c == 1) py[n] = v; else pz[n] = v;
  }
  const float* cc = centers + (size_t)bg * 3;
  const float cx = cc[0], cy = cc[1], cz = cc[2];
  const float aa = __fadd_rn(__fadd_rn(__fmul_rn(cx, cx), __fmul_rn(cy, cy)), __fmul_rn(cz, cz));
  __syncthreads();

  float bv = INFINITY; int bi = 0x7fffffff;
#pragma unroll
  for (int k = 0; k < 8; ++k) {
    int n = t + 256 * k;
    float X = px[n], Y = py[n], Z = pz[n];
    float bbv = __fadd_rn(__fadd_rn(__fmul_rn(X, X), __fmul_rn(Y, Y)), __fmul_rn(Z, Z));
    float dot = __fadd_rn(__fadd_rn(__fmul_rn(cx, X), __fmul_rn(cy, Y)), __fmul_rn(cz, Z));
    float d2 = __fsub_rn(__fadd_rn(aa, bbv), __fmul_rn(2.0f, dot));
    d2s[n] = d2;
    if (d2 < bv) { bv = d2; bi = n; }
  }
  lval[t] = bv; lidx[t] = bi;
  __syncthreads();

  for (int it = 0; it < Sn; ++it) {
    if (t < 64) {
      float v = INFINITY; int vi = 0x7fffffff; int vp = t;
      for (int p = t; p < 256; p += 64) {
        float fv = lval[p]; int fi = lidx[p];
        if (fv < v || (fv == v && fi < vi)) { v = fv; vi = fi; vp = p; }
      }
#pragma unroll
      for (int off = 32; off >= 1; off >>= 1) {
        float ov = __shfl_xor(v, off, 64);
        int   oi = __shfl_xor(vi, off, 64);
        int   op = __shfl_xor(vp, off, 64);
        if (ov < v || (ov == v && oi < vi)) { v = ov; vi = oi; vp = op; }
      }
      if (t == 0) {
        knn[(size_t)bg * Sn + it] = vi;
        if (it == 0) cidx[bg] = vi;
        sel[it] = vi;
        wpos = vp;
        d2s[vi] = INFINITY;
      }
    }
    __syncthreads();
    if (t == wpos) {
      float nb = INFINITY; int ni = 0x7fffffff;
#pragma unroll
      for (int k = 0; k < 8; ++k) {
        int n = t + 256 * k;
        float v = d2s[n];
        if (v < nb) { nb = v; ni = n; }
      }
      lval[t] = nb; lidx[t] = ni;
    }
    __syncthreads();
  }

  if (t < 96) {
    int s = t / 3, c = t - s * 3;
    int gi = sel[s];
    float pv = (c == 0) ? px[gi] : (c == 1) ? py[gi] : pz[gi];
    float cv = (c == 0) ? cx : (c == 1) ? cy : cz;
    float d = __fsub_rn(pv, cv);
    diffb[(size_t)bg * 96 + s * 3 + c] = d;
    tmp[t] = d;
  }
  __syncthreads();
  if (t == 0) {
    double s1 = 0.0, s2 = 0.0;
    for (int i = 0; i < 96; ++i) { double v = (double)tmp[i]; s1 += v; s2 += v * v; }
    atomicAdd(sums, s1);
    atomicAdd(sums + 1, s2);
  }
}

// ---------------------------------------------------------------------------
// Global std (unbiased) from fp64 sums
// ---------------------------------------------------------------------------
__global__ void stddev_kernel(const double* __restrict__ sums, float* __restrict__ stdp) {
  const double n = (double)(Bn * Gn * Sn * 3);
  double s1 = sums[0], s2 = sums[1];
  double mean = s1 / n;
  double var = (s2 - s1 * mean) / (n - 1.0);
  *stdp = (float)sqrt(var) + 1e-5f;
}

// ---------------------------------------------------------------------------
// GEMM1: X(gathered 2D concat) @ W1^T, +b1, ReLU, fused Fourier pos-embed
// epilogue: G1 = (y+pos)*pos -> bf16. 64x64 tile, 4 waves, 16x16x32 mfma.
// ---------------------------------------------------------------------------
__global__ __launch_bounds__(256) void gemm1_kernel(
    const float* __restrict__ feats, const unsigned short* __restrict__ W1b,
    const float* __restrict__ b1, const int* __restrict__ knn,
    const int* __restrict__ cidx, const float* __restrict__ diffb,
    const float* __restrict__ stdp_p, const float* __restrict__ denomTab,
    unsigned short* __restrict__ G1) {
  __shared__ unsigned short As[64 * 40];   // +8 bf16 pad: 2-way-free LDS banks
  __shared__ unsigned short Bs[64 * 40];
  const int t = threadIdx.x;
  const int bm = blockIdx.x, bn = blockIdx.y;
  const int wid = t >> 6, lane = t & 63, quad = lane >> 4, c16 = lane & 15;
  const int sr = t >> 2, sseg = t & 3;

  const int grow = bm * 64 + sr;
  const int bg = grow >> 5, s = grow & 31;
  const int b = bg >> 9;
  const int nidx = knn[(size_t)bg * Sn + s];
  const int ci = cidx[bg];
  const float* baseN = feats + ((size_t)(b * Nn + nidx)) * Dn;
  const float* baseC = feats + ((size_t)(b * Nn + ci)) * Dn;
  const unsigned short* wrow = W1b + (size_t)(bn * 64 + sr) * 384;

  floatx4 acc[4];
#pragma unroll
  for (int i = 0; i < 4; ++i) acc[i] = (floatx4){0.f, 0.f, 0.f, 0.f};

  for (int kt = 0; kt < 12; ++kt) {
    const int kb = kt * 32 + sseg * 8;
    const float* src = (kb < Dn) ? (baseN + kb) : (baseC + (kb - Dn));
    const float4* s4 = reinterpret_cast<const float4*>(src);
    float4 f0 = s4[0], f1 = s4[1];
    ushortx8 av;
    av[0] = f2bf(f0.x); av[1] = f2bf(f0.y); av[2] = f2bf(f0.z); av[3] = f2bf(f0.w);
    av[4] = f2bf(f1.x); av[5] = f2bf(f1.y); av[6] = f2bf(f1.z); av[7] = f2bf(f1.w);
    ushortx8 bv = *reinterpret_cast<const ushortx8*>(wrow + kt * 32 + sseg * 8);
    __syncthreads();
    *reinterpret_cast<ushortx8*>(&As[sr * 40 + sseg * 8]) = av;
    *reinterpret_cast<ushortx8*>(&Bs[sr * 40 + sseg * 8]) = bv;
    __syncthreads();
    ushortx8 bfrag = *reinterpret_cast<const ushortx8*>(&Bs[(wid * 16 + c16) * 40 + quad * 8]);
#pragma unroll
    for (int mt = 0; mt < 4; ++mt) {
      ushortx8 afrag = *reinterpret_cast<const ushortx8*>(&As[(mt * 16 + c16) * 40 + quad * 8]);
      acc[mt] = mfma_bf16(afrag, bfrag, acc[mt]);
    }
  }

  const int col = bn * 64 + wid * 16 + c16;
  const float bias = b1[col];
  const int i3 = col >> 7;
  const int j = col & 127;
  const int jj = j & 63;
  const bool use_sin = (j < 64);
  const float dnm = denomTab[jj];
  const float stdp = *stdp_p;
#pragma unroll
  for (int mt = 0; mt < 4; ++mt) {
#pragma unroll
    for (int r = 0; r < 4; ++r) {
      const int row = bm * 64 + mt * 16 + quad * 4 + r;
      float y = fmaxf(acc[mt][r] + bias, 0.f);
      float dv = diffb[(size_t)row * 3 + i3];
      float x = __fdiv_rn(dv, stdp);
      float z = __fdiv_rn(__fmul_rn(100.0f, x), dnm);
      float p = use_sin ? sinf(z) : cosf(z);
      float g = (y + p) * p;
      G1[(size_t)row * 384 + col] = f2bf(g);
    }
  }
}

// ---------------------------------------------------------------------------
// GEMM2: H = relu(G1 @ Wa^T + ba)  (K=384, N=192)
// ---------------------------------------------------------------------------
__global__ __launch_bounds__(256) void gemm2_kernel(
    const unsigned short* __restrict__ G1, const unsigned short* __restrict__ Wab,
    const float* __restrict__ ba, unsigned short* __restrict__ H) {
  __shared__ unsigned short As[64 * 40];
  __shared__ unsigned short Bs[64 * 40];
  const int t = threadIdx.x;
  const int bm = blockIdx.x, bn = blockIdx.y;
  const int wid = t >> 6, lane = t & 63, quad = lane >> 4, c16 = lane & 15;
  const int sr = t >> 2, sseg = t & 3;

  const int grow = bm * 64 + sr;
  const unsigned short* arow = G1 + (size_t)grow * 384;
  const unsigned short* wrow = Wab + (size_t)(bn * 64 + sr) * 384;

  floatx4 acc[4];
#pragma unroll
  for (int i = 0; i < 4; ++i) acc[i] = (floatx4){0.f, 0.f, 0.f, 0.f};

  for (int kt = 0; kt < 12; ++kt) {
    const int kb = kt * 32 + sseg * 8;
    ushortx8 av = *reinterpret_cast<const ushortx8*>(arow + kb);
    ushortx8 bv = *reinterpret_cast<const ushortx8*>(wrow + kb);
    __syncthreads();
    *reinterpret_cast<ushortx8*>(&As[sr * 40 + sseg * 8]) = av;
    *reinterpret_cast<ushortx8*>(&Bs[sr * 40 + sseg * 8]) = bv;
    __syncthreads();
    ushortx8 bfrag = *reinterpret_cast<const ushortx8*>(&Bs[(wid * 16 + c16) * 40 + quad * 8]);
#pragma unroll
    for (int mt = 0; mt < 4; ++mt) {
      ushortx8 afrag = *reinterpret_cast<const ushortx8*>(&As[(mt * 16 + c16) * 40 + quad * 8]);
      acc[mt] = mfma_bf16(afrag, bfrag, acc[mt]);
    }
  }

  const int col = bn * 64 + wid * 16 + c16;   // < 192
  const float bias = ba[col];
#pragma unroll
  for (int mt = 0; mt < 4; ++mt) {
#pragma unroll
    for (int r = 0; r < 4; ++r) {
      const int row = bm * 64 + mt * 16 + quad * 4 + r;
      float h = fmaxf(acc[mt][r] + bias, 0.f);
      H[(size_t)row * 192 + col] = f2bf(h);
    }
  }
}

// ---------------------------------------------------------------------------
// GEMM3: relu(H @ Wb^T + bb + G1) then fused max+mean pooling over S=32 rows.
// 64-row tile = 2 groups; cross-quad shfl_xor reduction; writes d_out directly.
// ---------------------------------------------------------------------------
__global__ __launch_bounds__(256) void gemm3_kernel(
    const unsigned short* __restrict__ H, const unsigned short* __restrict__ Wbb,
    const float* __restrict__ bb, const unsigned short* __restrict__ G1,
    float* __restrict__ outp) {
  __shared__ unsigned short As[64 * 40];
  __shared__ unsigned short Bs[64 * 40];
  const int t = threadIdx.x;
  const int bm = blockIdx.x, bn = blockIdx.y;
  const int wid = t >> 6, lane = t & 63, quad = lane >> 4, c16 = lane & 15;
  const int sr = t >> 2, sseg = t & 3;

  const int grow = bm * 64 + sr;
  const unsigned short* arow = H + (size_t)grow * 192;
  const unsigned short* wrow = Wbb + (size_t)(bn * 64 + sr) * 192;

  floatx4 acc[4];
#pragma unroll
  for (int i = 0; i < 4; ++i) acc[i] = (floatx4){0.f, 0.f, 0.f, 0.f};

  for (int kt = 0; kt < 6; ++kt) {
    const int kb = kt * 32 + sseg * 8;
    ushortx8 av = *reinterpret_cast<const ushortx8*>(arow + kb);
    ushortx8 bv = *reinterpret_cast<const ushortx8*>(wrow + kb);
    __syncthreads();
    *reinterpret_cast<ushortx8*>(&As[sr * 40 + sseg * 8]) = av;
    *reinterpret_cast<ushortx8*>(&Bs[sr * 40 + sseg * 8]) = bv;
    __syncthreads();
    ushortx8 bfrag = *reinterpret_cast<const ushortx8*>(&Bs[(wid * 16 + c16) * 40 + quad * 8]);
#pragma unroll
    for (int mt = 0; mt < 4; ++mt) {
      ushortx8 afrag = *reinterpret_cast<const ushortx8*>(&As[(mt * 16 + c16) * 40 + quad * 8]);
      acc[mt] = mfma_bf16(afrag, bfrag, acc[mt]);
    }
  }

  const int col = bn * 64 + wid * 16 + c16;
  const float bias = bb[col];
  float gmax[2] = {-INFINITY, -INFINITY};
  float gsum[2] = {0.f, 0.f};
#pragma unroll
  for (int mt = 0; mt < 4; ++mt) {
    const int grp = mt >> 1;
#pragma unroll
    for (int r = 0; r < 4; ++r) {
      const int row = bm * 64 + mt * 16 + quad * 4 + r;
      float v = acc[mt][r] + bias + bf2f(G1[(size_t)row * 384 + col]);
      v = fmaxf(v, 0.f);
      gmax[grp] = fmaxf(gmax[grp], v);
      gsum[grp] += v;
    }
  }
#pragma unroll
  for (int grp = 0; grp < 2; ++grp) {
    float m = gmax[grp], su = gsum[grp];
#pragma unroll
    for (int off = 16; off <= 32; off <<= 1) {
      m = fmaxf(m, __shfl_xor(m, off, 64));
      su += __shfl_xor(su, off, 64);
    }
    if (quad == 0) {
      const int bg = bm * 2 + grp;
      outp[(size_t)bg * 384 + col] = m + su / 32.0f;
    }
  }
}

// ---------------------------------------------------------------------------
extern "C" void kernel_launch(void* const* d_in, const int* in_sizes, int n_in,
                              void* d_out, int out_size, void* d_ws, size_t ws_size,
                              hipStream_t stream) {
  const float* points = (const float*)d_in[0];
  const float* feats  = (const float*)d_in[1];
  const float* W1 = (const float*)d_in[2];
  const float* b1 = (const float*)d_in[3];
  const float* Wa = (const float*)d_in[4];
  const float* ba = (const float*)d_in[5];
  const float* Wb = (const float*)d_in[6];
  const float* bb = (const float*)d_in[7];
  float* outF = (float*)d_out;

  char* ws = (char*)d_ws;
  int*            knn      = (int*)(ws + OFF_KNN);
  int*            cidx     = (int*)(ws + OFF_CIDX);
  float*          diffb    = (float*)(ws + OFF_DIFF);
  double*         sums     = (double*)(ws + OFF_SUMS);
  float*          stdp     = (float*)(ws + OFF_STD);
  float*          denomTab = (float*)(ws + OFF_DENOM);
  unsigned short* W1b      = (unsigned short*)(ws + OFF_W1B);
  unsigned short* Wab      = (unsigned short*)(ws + OFF_WAB);
  unsigned short* Wbb      = (unsigned short*)(ws + OFF_WBB);
  unsigned short* G1       = (unsigned short*)(ws + OFF_G1);
  unsigned short* H        = (unsigned short*)(ws + OFF_H);

  hipMemsetAsync(sums, 0, 2 * sizeof(double), stream);
  prep_kernel<<<1152, 256, 0, stream>>>(W1, Wa, Wb, W1b, Wab, Wbb, denomTab);
  fps_kernel<<<Bn, 256, 0, stream>>>(points, outF);
  knn_kernel<<<Bn * Gn, 256, 0, stream>>>(points, outF, knn, cidx, diffb, sums);
  stddev_kernel<<<1, 1, 0, stream>>>(sums, stdp);
  gemm1_kernel<<<dim3(Mrows / 64, 6), 256, 0, stream>>>(feats, W1b, b1, knn, cidx,
                                                        diffb, stdp, denomTab, G1);
  gemm2_kernel<<<dim3(Mrows / 64, 3), 256, 0, stream>>>(G1, Wab, ba, H);
  gemm3_kernel<<<dim3(Mrows / 64, 6), 256, 0, stream>>>(H, Wbb, bb, G1, outF + Bn * Gn * 3);
}

// Round 2
// 1012.691 us; speedup vs baseline: 1.2107x; 1.2107x over previous
//
#include <hip/hip_runtime.h>
#include <math.h>

// Problem constants
#define Bn   8
#define Nn   2048
#define Dn   192
#define Gn   512
#define Sn   32
#define OUTn 384
#define Mrows (Bn * Gn * Sn)   // 131072 rows through the MLP

typedef __attribute__((ext_vector_type(8))) unsigned short ushortx8;
typedef __attribute__((ext_vector_type(8))) __bf16 bf16x8;
typedef __attribute__((ext_vector_type(4))) float floatx4;

// ---------- ws layout (bytes) ----------
static constexpr size_t OFF_KNN   = 0;                    // 131072 * 4
static constexpr size_t OFF_CIDX  = 524288;               // 4096 * 4
static constexpr size_t OFF_DIFF  = 540672;               // 393216 * 4
static constexpr size_t OFF_SUMS  = 2113536;              // 2 doubles
static constexpr size_t OFF_STD   = 2113552;              // 1 float
static constexpr size_t OFF_DENOM = 2113792;              // 64 floats
static constexpr size_t OFF_W1B   = 2114048;              // 147456 * 2
static constexpr size_t OFF_WAB   = 2408960;              // 73728 * 2
static constexpr size_t OFF_WBB   = 2556416;              // 73728 * 2
static constexpr size_t OFF_G1    = 2703872;              // 50331648 * 2
static constexpr size_t OFF_H     = 103367168;            // 25165824 * 2
// total ~153.7 MB

__device__ __forceinline__ unsigned short f2bf(float f) {
  unsigned u = __float_as_uint(f);
  unsigned r = (u + 0x7FFFu + ((u >> 16) & 1u)) >> 16;   // RNE
  return (unsigned short)r;
}
__device__ __forceinline__ float bf2f(unsigned short h) {
  return __uint_as_float(((unsigned)h) << 16);
}
__device__ __forceinline__ floatx4 mfma_bf16(ushortx8 a, ushortx8 b, floatx4 c) {
  return __builtin_amdgcn_mfma_f32_16x16x32_bf16(
      __builtin_bit_cast(bf16x8, a), __builtin_bit_cast(bf16x8, b), c, 0, 0, 0);
}

// ---------------------------------------------------------------------------
// prep: fp32 weights -> bf16, and Fourier denom table
// ---------------------------------------------------------------------------
__global__ void prep_kernel(const float* __restrict__ W1, const float* __restrict__ Wa,
                            const float* __restrict__ Wb,
                            unsigned short* __restrict__ W1b, unsigned short* __restrict__ Wab,
                            unsigned short* __restrict__ Wbb, float* __restrict__ denomTab) {
  int i = blockIdx.x * 256 + threadIdx.x;
  if (i < 147456)            W1b[i] = f2bf(W1[i]);
  else if (i < 221184)       Wab[i - 147456] = f2bf(Wa[i - 147456]);
  else if (i < 294912)       Wbb[i - 221184] = f2bf(Wb[i - 221184]);
  if (blockIdx.x == 0 && threadIdx.x < 64)
    denomTab[threadIdx.x] = (float)pow(1000.0, (double)threadIdx.x / 64.0);
}

// ---------------------------------------------------------------------------
// FPS (latency-optimized): one block (4 waves) per batch, 8 pts/lane.
//  - ONE barrier per iteration (double-buffered wave slots)
//  - (val,idx) packed into uint64: hi=fp32 bits (nonneg -> bit order == float
//    order), lo = 0x7FFFFFFF - idx  => u64-max == argmax w/ first-index ties.
//  - points as float4 in LDS: p[cur] fetch = one broadcast ds_read_b128.
// Selection arithmetic bit-identical to numpy ref (no FMA contraction).
// ---------------------------------------------------------------------------
__global__ __launch_bounds__(256) void fps_kernel(const float* __restrict__ points,
                                                  float* __restrict__ centers) {
  const int b = blockIdx.x;
  const int t = threadIdx.x;
  const int w = t >> 6, lane = t & 63;
  __shared__ float4 p4[Nn];
  __shared__ unsigned long long wkey[2][4];

  const float* P = points + (size_t)b * Nn * 3;
  for (int n = t; n < Nn; n += 256) {
    float x = P[n * 3], y = P[n * 3 + 1], z = P[n * 3 + 2];
    p4[n] = make_float4(x, y, z, 0.f);
  }
  __syncthreads();

  float rx[8], ry[8], rz[8], dist[8];
#pragma unroll
  for (int k = 0; k < 8; ++k) {
    float4 p = p4[t + 256 * k];
    rx[k] = p.x; ry[k] = p.y; rz[k] = p.z;
    dist[k] = INFINITY;
  }

  int cur = 0;
  for (int it = 0; it < Gn; ++it) {
    const float4 c = p4[cur];
    if (t == 0) {
      float* cd = centers + ((size_t)b * Gn + it) * 3;
      cd[0] = c.x; cd[1] = c.y; cd[2] = c.z;
    }
    float bv = -1.0f; int bn = 0;
#pragma unroll
    for (int k = 0; k < 8; ++k) {
      float dx = __fsub_rn(rx[k], c.x);
      float dy = __fsub_rn(ry[k], c.y);
      float dz = __fsub_rn(rz[k], c.z);
      float d = __fadd_rn(__fadd_rn(__fmul_rn(dx, dx), __fmul_rn(dy, dy)), __fmul_rn(dz, dz));
      dist[k] = fminf(dist[k], d);
      if (dist[k] > bv) { bv = dist[k]; bn = t + 256 * k; }   // strict >: first idx wins
    }
    unsigned long long key =
        ((unsigned long long)__float_as_uint(bv) << 32) | (unsigned)(0x7FFFFFFF - bn);
#pragma unroll
    for (int off = 1; off <= 32; off <<= 1) {
      unsigned long long o = __shfl_xor(key, off, 64);
      key = (o > key) ? o : key;
    }
    if (lane == 0) wkey[it & 1][w] = key;
    __syncthreads();
    unsigned long long k0 = wkey[it & 1][0];
    unsigned long long k1 = wkey[it & 1][1];
    unsigned long long k2 = wkey[it & 1][2];
    unsigned long long k3 = wkey[it & 1][3];
    unsigned long long m01 = (k1 > k0) ? k1 : k0;
    unsigned long long m23 = (k3 > k2) ? k3 : k2;
    unsigned long long mm = (m23 > m01) ? m23 : m01;
    cur = 0x7FFFFFFF - (int)(unsigned)mm;
  }
}

// ---------------------------------------------------------------------------
// KNN: one block per (b,g). Exact d2 = (aa+bb) - 2*dot (np association),
// leader-based exact top-32 extraction (lowest-index tie-break, matches
// lax.top_k / argmin). Also emits diff and fp64 partial sums for global std.
// ---------------------------------------------------------------------------
__global__ __launch_bounds__(256) void knn_kernel(const float* __restrict__ points,
                                                  const float* __restrict__ centers,
                                                  int* __restrict__ knn, int* __restrict__ cidx,
                                                  float* __restrict__ diffb,
                                                  double* __restrict__ sums) {
  const int bg = blockIdx.x;
  const int b = bg >> 9;
  const int t = threadIdx.x;
  __shared__ float px[Nn], py[Nn], pz[Nn];
  __shared__ float d2s[Nn];
  __shared__ float lval[256];
  __shared__ int   lidx[256];
  __shared__ int   sel[Sn];
  __shared__ int   wpos;
  __shared__ float tmp[96];

  const float* P = points + (size_t)b * Nn * 3;
  for (int i = t; i < Nn * 3; i += 256) {
    float v = P[i];
    int n = i / 3, c = i - n * 3;
    if (c == 0) px[n] = v; else if (c == 1) py[n] = v; else pz[n] = v;
  }
  const float* cc = centers + (size_t)bg * 3;
  const float cx = cc[0], cy = cc[1], cz = cc[2];
  const float aa = __fadd_rn(__fadd_rn(__fmul_rn(cx, cx), __fmul_rn(cy, cy)), __fmul_rn(cz, cz));
  __syncthreads();

  float bv = INFINITY; int bi = 0x7fffffff;
#pragma unroll
  for (int k = 0; k < 8; ++k) {
    int n = t + 256 * k;
    float X = px[n], Y = py[n], Z = pz[n];
    float bbv = __fadd_rn(__fadd_rn(__fmul_rn(X, X), __fmul_rn(Y, Y)), __fmul_rn(Z, Z));
    float dot = __fadd_rn(__fadd_rn(__fmul_rn(cx, X), __fmul_rn(cy, Y)), __fmul_rn(cz, Z));
    float d2 = __fsub_rn(__fadd_rn(aa, bbv), __fmul_rn(2.0f, dot));
    d2s[n] = d2;
    if (d2 < bv) { bv = d2; bi = n; }
  }
  lval[t] = bv; lidx[t] = bi;
  __syncthreads();

  for (int it = 0; it < Sn; ++it) {
    if (t < 64) {
      float v = INFINITY; int vi = 0x7fffffff; int vp = t;
      for (int p = t; p < 256; p += 64) {
        float fv = lval[p]; int fi = lidx[p];
        if (fv < v || (fv == v && fi < vi)) { v = fv; vi = fi; vp = p; }
      }
#pragma unroll
      for (int off = 32; off >= 1; off >>= 1) {
        float ov = __shfl_xor(v, off, 64);
        int   oi = __shfl_xor(vi, off, 64);
        int   op = __shfl_xor(vp, off, 64);
        if (ov < v || (ov == v && oi < vi)) { v = ov; vi = oi; vp = op; }
      }
      if (t == 0) {
        knn[(size_t)bg * Sn + it] = vi;
        if (it == 0) cidx[bg] = vi;
        sel[it] = vi;
        wpos = vp;
        d2s[vi] = INFINITY;
      }
    }
    __syncthreads();
    if (t == wpos) {
      float nb = INFINITY; int ni = 0x7fffffff;
#pragma unroll
      for (int k = 0; k < 8; ++k) {
        int n = t + 256 * k;
        float v = d2s[n];
        if (v < nb) { nb = v; ni = n; }
      }
      lval[t] = nb; lidx[t] = ni;
    }
    __syncthreads();
  }

  if (t < 96) {
    int s = t / 3, c = t - s * 3;
    int gi = sel[s];
    float pv = (c == 0) ? px[gi] : (c == 1) ? py[gi] : pz[gi];
    float cv = (c == 0) ? cx : (c == 1) ? cy : cz;
    float d = __fsub_rn(pv, cv);
    diffb[(size_t)bg * 96 + s * 3 + c] = d;
    tmp[t] = d;
  }
  __syncthreads();
  if (t == 0) {
    double s1 = 0.0, s2 = 0.0;
    for (int i = 0; i < 96; ++i) { double v = (double)tmp[i]; s1 += v; s2 += v * v; }
    atomicAdd(sums, s1);
    atomicAdd(sums + 1, s2);
  }
}

// ---------------------------------------------------------------------------
// Global std (unbiased) from fp64 sums
// ---------------------------------------------------------------------------
__global__ void stddev_kernel(const double* __restrict__ sums, float* __restrict__ stdp) {
  const double n = (double)(Bn * Gn * Sn * 3);
  double s1 = sums[0], s2 = sums[1];
  double mean = s1 / n;
  double var = (s2 - s1 * mean) / (n - 1.0);
  *stdp = (float)sqrt(var) + 1e-5f;
}

// ---------------------------------------------------------------------------
// GEMM1: X(gathered 2D concat) @ W1^T, +b1, ReLU, fused Fourier pos-embed
// epilogue: G1 = (y+pos)*pos -> bf16. 64x64 tile, 4 waves, 16x16x32 mfma.
// ---------------------------------------------------------------------------
__global__ __launch_bounds__(256) void gemm1_kernel(
    const float* __restrict__ feats, const unsigned short* __restrict__ W1b,
    const float* __restrict__ b1, const int* __restrict__ knn,
    const int* __restrict__ cidx, const float* __restrict__ diffb,
    const float* __restrict__ stdp_p, const float* __restrict__ denomTab,
    unsigned short* __restrict__ G1) {
  __shared__ unsigned short As[64 * 40];   // +8 bf16 pad: 2-way-free LDS banks
  __shared__ unsigned short Bs[64 * 40];
  const int t = threadIdx.x;
  const int bm = blockIdx.x, bn = blockIdx.y;
  const int wid = t >> 6, lane = t & 63, quad = lane >> 4, c16 = lane & 15;
  const int sr = t >> 2, sseg = t & 3;

  const int grow = bm * 64 + sr;
  const int bg = grow >> 5, s = grow & 31;
  const int b = bg >> 9;
  const int nidx = knn[(size_t)bg * Sn + s];
  const int ci = cidx[bg];
  const float* baseN = feats + ((size_t)(b * Nn + nidx)) * Dn;
  const float* baseC = feats + ((size_t)(b * Nn + ci)) * Dn;
  const unsigned short* wrow = W1b + (size_t)(bn * 64 + sr) * 384;

  floatx4 acc[4];
#pragma unroll
  for (int i = 0; i < 4; ++i) acc[i] = (floatx4){0.f, 0.f, 0.f, 0.f};

  for (int kt = 0; kt < 12; ++kt) {
    const int kb = kt * 32 + sseg * 8;
    const float* src = (kb < Dn) ? (baseN + kb) : (baseC + (kb - Dn));
    const float4* s4 = reinterpret_cast<const float4*>(src);
    float4 f0 = s4[0], f1 = s4[1];
    ushortx8 av;
    av[0] = f2bf(f0.x); av[1] = f2bf(f0.y); av[2] = f2bf(f0.z); av[3] = f2bf(f0.w);
    av[4] = f2bf(f1.x); av[5] = f2bf(f1.y); av[6] = f2bf(f1.z); av[7] = f2bf(f1.w);
    ushortx8 bv = *reinterpret_cast<const ushortx8*>(wrow + kt * 32 + sseg * 8);
    __syncthreads();
    *reinterpret_cast<ushortx8*>(&As[sr * 40 + sseg * 8]) = av;
    *reinterpret_cast<ushortx8*>(&Bs[sr * 40 + sseg * 8]) = bv;
    __syncthreads();
    ushortx8 bfrag = *reinterpret_cast<const ushortx8*>(&Bs[(wid * 16 + c16) * 40 + quad * 8]);
#pragma unroll
    for (int mt = 0; mt < 4; ++mt) {
      ushortx8 afrag = *reinterpret_cast<const ushortx8*>(&As[(mt * 16 + c16) * 40 + quad * 8]);
      acc[mt] = mfma_bf16(afrag, bfrag, acc[mt]);
    }
  }

  const int col = bn * 64 + wid * 16 + c16;
  const float bias = b1[col];
  const int i3 = col >> 7;
  const int j = col & 127;
  const int jj = j & 63;
  const bool use_sin = (j < 64);
  const float dnm = denomTab[jj];
  const float stdp = *stdp_p;
#pragma unroll
  for (int mt = 0; mt < 4; ++mt) {
#pragma unroll
    for (int r = 0; r < 4; ++r) {
      const int row = bm * 64 + mt * 16 + quad * 4 + r;
      float y = fmaxf(acc[mt][r] + bias, 0.f);
      float dv = diffb[(size_t)row * 3 + i3];
      float x = __fdiv_rn(dv, stdp);
      float z = __fdiv_rn(__fmul_rn(100.0f, x), dnm);
      float p = use_sin ? sinf(z) : cosf(z);
      float g = (y + p) * p;
      G1[(size_t)row * 384 + col] = f2bf(g);
    }
  }
}

// ---------------------------------------------------------------------------
// GEMM2: H = relu(G1 @ Wa^T + ba)  (K=384, N=192)
// ---------------------------------------------------------------------------
__global__ __launch_bounds__(256) void gemm2_kernel(
    const unsigned short* __restrict__ G1, const unsigned short* __restrict__ Wab,
    const float* __restrict__ ba, unsigned short* __restrict__ H) {
  __shared__ unsigned short As[64 * 40];
  __shared__ unsigned short Bs[64 * 40];
  const int t = threadIdx.x;
  const int bm = blockIdx.x, bn = blockIdx.y;
  const int wid = t >> 6, lane = t & 63, quad = lane >> 4, c16 = lane & 15;
  const int sr = t >> 2, sseg = t & 3;

  const int grow = bm * 64 + sr;
  const unsigned short* arow = G1 + (size_t)grow * 384;
  const unsigned short* wrow = Wab + (size_t)(bn * 64 + sr) * 384;

  floatx4 acc[4];
#pragma unroll
  for (int i = 0; i < 4; ++i) acc[i] = (floatx4){0.f, 0.f, 0.f, 0.f};

  for (int kt = 0; kt < 12; ++kt) {
    const int kb = kt * 32 + sseg * 8;
    ushortx8 av = *reinterpret_cast<const ushortx8*>(arow + kb);
    ushortx8 bv = *reinterpret_cast<const ushortx8*>(wrow + kb);
    __syncthreads();
    *reinterpret_cast<ushortx8*>(&As[sr * 40 + sseg * 8]) = av;
    *reinterpret_cast<ushortx8*>(&Bs[sr * 40 + sseg * 8]) = bv;
    __syncthreads();
    ushortx8 bfrag = *reinterpret_cast<const ushortx8*>(&Bs[(wid * 16 + c16) * 40 + quad * 8]);
#pragma unroll
    for (int mt = 0; mt < 4; ++mt) {
      ushortx8 afrag = *reinterpret_cast<const ushortx8*>(&As[(mt * 16 + c16) * 40 + quad * 8]);
      acc[mt] = mfma_bf16(afrag, bfrag, acc[mt]);
    }
  }

  const int col = bn * 64 + wid * 16 + c16;   // < 192
  const float bias = ba[col];
#pragma unroll
  for (int mt = 0; mt < 4; ++mt) {
#pragma unroll
    for (int r = 0; r < 4; ++r) {
      const int row = bm * 64 + mt * 16 + quad * 4 + r;
      float h = fmaxf(acc[mt][r] + bias, 0.f);
      H[(size_t)row * 192 + col] = f2bf(h);
    }
  }
}

// ---------------------------------------------------------------------------
// GEMM3: relu(H @ Wb^T + bb + G1) then fused max+mean pooling over S=32 rows.
// 64-row tile = 2 groups; cross-quad shfl_xor reduction; writes d_out directly.
// ---------------------------------------------------------------------------
__global__ __launch_bounds__(256) void gemm3_kernel(
    const unsigned short* __restrict__ H, const unsigned short* __restrict__ Wbb,
    const float* __restrict__ bb, const unsigned short* __restrict__ G1,
    float* __restrict__ outp) {
  __shared__ unsigned short As[64 * 40];
  __shared__ unsigned short Bs[64 * 40];
  const int t = threadIdx.x;
  const int bm = blockIdx.x, bn = blockIdx.y;
  const int wid = t >> 6, lane = t & 63, quad = lane >> 4, c16 = lane & 15;
  const int sr = t >> 2, sseg = t & 3;

  const int grow = bm * 64 + sr;
  const unsigned short* arow = H + (size_t)grow * 192;
  const unsigned short* wrow = Wbb + (size_t)(bn * 64 + sr) * 192;

  floatx4 acc[4];
#pragma unroll
  for (int i = 0; i < 4; ++i) acc[i] = (floatx4){0.f, 0.f, 0.f, 0.f};

  for (int kt = 0; kt < 6; ++kt) {
    const int kb = kt * 32 + sseg * 8;
    ushortx8 av = *reinterpret_cast<const ushortx8*>(arow + kb);
    ushortx8 bv = *reinterpret_cast<const ushortx8*>(wrow + kb);
    __syncthreads();
    *reinterpret_cast<ushortx8*>(&As[sr * 40 + sseg * 8]) = av;
    *reinterpret_cast<ushortx8*>(&Bs[sr * 40 + sseg * 8]) = bv;
    __syncthreads();
    ushortx8 bfrag = *reinterpret_cast<const ushortx8*>(&Bs[(wid * 16 + c16) * 40 + quad * 8]);
#pragma unroll
    for (int mt = 0; mt < 4; ++mt) {
      ushortx8 afrag = *reinterpret_cast<const ushortx8*>(&As[(mt * 16 + c16) * 40 + quad * 8]);
      acc[mt] = mfma_bf16(afrag, bfrag, acc[mt]);
    }
  }

  const int col = bn * 64 + wid * 16 + c16;
  const float bias = bb[col];
  float gmax[2] = {-INFINITY, -INFINITY};
  float gsum[2] = {0.f, 0.f};
#pragma unroll
  for (int mt = 0; mt < 4; ++mt) {
    const int grp = mt >> 1;
#pragma unroll
    for (int r = 0; r < 4; ++r) {
      const int row = bm * 64 + mt * 16 + quad * 4 + r;
      float v = acc[mt][r] + bias + bf2f(G1[(size_t)row * 384 + col]);
      v = fmaxf(v, 0.f);
      gmax[grp] = fmaxf(gmax[grp], v);
      gsum[grp] += v;
    }
  }
#pragma unroll
  for (int grp = 0; grp < 2; ++grp) {
    float m = gmax[grp], su = gsum[grp];
#pragma unroll
    for (int off = 16; off <= 32; off <<= 1) {
      m = fmaxf(m, __shfl_xor(m, off, 64));
      su += __shfl_xor(su, off, 64);
    }
    if (quad == 0) {
      const int bg = bm * 2 + grp;
      outp[(size_t)bg * 384 + col] = m + su / 32.0f;
    }
  }
}

// ---------------------------------------------------------------------------
extern "C" void kernel_launch(void* const* d_in, const int* in_sizes, int n_in,
                              void* d_out, int out_size, void* d_ws, size_t ws_size,
                              hipStream_t stream) {
  const float* points = (const float*)d_in[0];
  const float* feats  = (const float*)d_in[1];
  const float* W1 = (const float*)d_in[2];
  const float* b1 = (const float*)d_in[3];
  const float* Wa = (const float*)d_in[4];
  const float* ba = (const float*)d_in[5];
  const float* Wb = (const float*)d_in[6];
  const float* bb = (const float*)d_in[7];
  float* outF = (float*)d_out;

  char* ws = (char*)d_ws;
  int*            knn      = (int*)(ws + OFF_KNN);
  int*            cidx     = (int*)(ws + OFF_CIDX);
  float*          diffb    = (float*)(ws + OFF_DIFF);
  double*         sums     = (double*)(ws + OFF_SUMS);
  float*          stdp     = (float*)(ws + OFF_STD);
  float*          denomTab = (float*)(ws + OFF_DENOM);
  unsigned short* W1b      = (unsigned short*)(ws + OFF_W1B);
  unsigned short* Wab      = (unsigned short*)(ws + OFF_WAB);
  unsigned short* Wbb      = (unsigned short*)(ws + OFF_WBB);
  unsigned short* G1       = (unsigned short*)(ws + OFF_G1);
  unsigned short* H        = (unsigned short*)(ws + OFF_H);

  hipMemsetAsync(sums, 0, 2 * sizeof(double), stream);
  prep_kernel<<<1152, 256, 0, stream>>>(W1, Wa, Wb, W1b, Wab, Wbb, denomTab);
  fps_kernel<<<Bn, 256, 0, stream>>>(points, outF);
  knn_kernel<<<Bn * Gn, 256, 0, stream>>>(points, outF, knn, cidx, diffb, sums);
  stddev_kernel<<<1, 1, 0, stream>>>(sums, stdp);
  gemm1_kernel<<<dim3(Mrows / 64, 6), 256, 0, stream>>>(feats, W1b, b1, knn, cidx,
                                                        diffb, stdp, denomTab, G1);
  gemm2_kernel<<<dim3(Mrows / 64, 3), 256, 0, stream>>>(G1, Wab, ba, H);
  gemm3_kernel<<<dim3(Mrows / 64, 6), 256, 0, stream>>>(H, Wbb, bb, G1, outF + Bn * Gn * 3);
}

// Round 3
// 772.815 us; speedup vs baseline: 1.5865x; 1.3104x over previous
//
#include <hip/hip_runtime.h>
#include <math.h>

// Problem constants
#define Bn   8
#define Nn   2048
#define Dn   192
#define Gn   512
#define Sn   32
#define OUTn 384
#define Mrows (Bn * Gn * Sn)   // 131072 rows through the MLP

typedef __attribute__((ext_vector_type(8))) unsigned short ushortx8;
typedef __attribute__((ext_vector_type(8))) __bf16 bf16x8;
typedef __attribute__((ext_vector_type(4))) float floatx4;

// ---------- ws layout (bytes) ----------
static constexpr size_t OFF_KNN   = 0;                    // 131072 * 4
static constexpr size_t OFF_CIDX  = 524288;               // 4096 * 4
static constexpr size_t OFF_DIFF  = 540672;               // 393216 * 4
static constexpr size_t OFF_SUMS  = 2113536;              // 2 doubles
static constexpr size_t OFF_STD   = 2113552;              // 1 float
static constexpr size_t OFF_DENOM = 2113792;              // 64 floats
static constexpr size_t OFF_W1B   = 2114048;              // 147456 * 2
static constexpr size_t OFF_WAB   = 2408960;              // 73728 * 2
static constexpr size_t OFF_WBB   = 2556416;              // 73728 * 2
static constexpr size_t OFF_G1    = 2703872;              // 50331648 * 2
static constexpr size_t OFF_H     = 103367168;            // 25165824 * 2
// total ~153.7 MB

__device__ __forceinline__ unsigned short f2bf(float f) {
  unsigned u = __float_as_uint(f);
  unsigned r = (u + 0x7FFFu + ((u >> 16) & 1u)) >> 16;   // RNE
  return (unsigned short)r;
}
__device__ __forceinline__ float bf2f(unsigned short h) {
  return __uint_as_float(((unsigned)h) << 16);
}
__device__ __forceinline__ floatx4 mfma_bf16(ushortx8 a, ushortx8 b, floatx4 c) {
  return __builtin_amdgcn_mfma_f32_16x16x32_bf16(
      __builtin_bit_cast(bf16x8, a), __builtin_bit_cast(bf16x8, b), c, 0, 0, 0);
}

// ---------------------------------------------------------------------------
// prep: fp32 weights -> bf16, and Fourier denom table
// ---------------------------------------------------------------------------
__global__ void prep_kernel(const float* __restrict__ W1, const float* __restrict__ Wa,
                            const float* __restrict__ Wb,
                            unsigned short* __restrict__ W1b, unsigned short* __restrict__ Wab,
                            unsigned short* __restrict__ Wbb, float* __restrict__ denomTab) {
  int i = blockIdx.x * 256 + threadIdx.x;
  if (i < 147456)            W1b[i] = f2bf(W1[i]);
  else if (i < 221184)       Wab[i - 147456] = f2bf(Wa[i - 147456]);
  else if (i < 294912)       Wbb[i - 221184] = f2bf(Wb[i - 221184]);
  if (blockIdx.x == 0 && threadIdx.x < 64)
    denomTab[threadIdx.x] = (float)pow(1000.0, (double)threadIdx.x / 64.0);
}

// ---------------------------------------------------------------------------
// FPS (latency-optimized): one block (4 waves) per batch, 8 pts/lane.
//  - ONE barrier per iteration (double-buffered wave slots)
//  - (val,idx) packed into uint64: hi=fp32 bits, lo = 0x7FFFFFFF - idx
//  - points as float4 in LDS: p[cur] fetch = one broadcast ds_read_b128.
// Selection arithmetic bit-identical to numpy ref (no FMA contraction).
// ---------------------------------------------------------------------------
__global__ __launch_bounds__(256) void fps_kernel(const float* __restrict__ points,
                                                  float* __restrict__ centers) {
  const int b = blockIdx.x;
  const int t = threadIdx.x;
  const int w = t >> 6, lane = t & 63;
  __shared__ float4 p4[Nn];
  __shared__ unsigned long long wkey[2][4];

  const float* P = points + (size_t)b * Nn * 3;
  for (int n = t; n < Nn; n += 256) {
    float x = P[n * 3], y = P[n * 3 + 1], z = P[n * 3 + 2];
    p4[n] = make_float4(x, y, z, 0.f);
  }
  __syncthreads();

  float rx[8], ry[8], rz[8], dist[8];
#pragma unroll
  for (int k = 0; k < 8; ++k) {
    float4 p = p4[t + 256 * k];
    rx[k] = p.x; ry[k] = p.y; rz[k] = p.z;
    dist[k] = INFINITY;
  }

  int cur = 0;
  for (int it = 0; it < Gn; ++it) {
    const float4 c = p4[cur];
    if (t == 0) {
      float* cd = centers + ((size_t)b * Gn + it) * 3;
      cd[0] = c.x; cd[1] = c.y; cd[2] = c.z;
    }
    float bv = -1.0f; int bn = 0;
#pragma unroll
    for (int k = 0; k < 8; ++k) {
      float dx = __fsub_rn(rx[k], c.x);
      float dy = __fsub_rn(ry[k], c.y);
      float dz = __fsub_rn(rz[k], c.z);
      float d = __fadd_rn(__fadd_rn(__fmul_rn(dx, dx), __fmul_rn(dy, dy)), __fmul_rn(dz, dz));
      dist[k] = fminf(dist[k], d);
      if (dist[k] > bv) { bv = dist[k]; bn = t + 256 * k; }   // strict >: first idx wins
    }
    unsigned long long key =
        ((unsigned long long)__float_as_uint(bv) << 32) | (unsigned)(0x7FFFFFFF - bn);
#pragma unroll
    for (int off = 1; off <= 32; off <<= 1) {
      unsigned long long o = __shfl_xor(key, off, 64);
      key = (o > key) ? o : key;
    }
    if (lane == 0) wkey[it & 1][w] = key;
    __syncthreads();
    unsigned long long k0 = wkey[it & 1][0];
    unsigned long long k1 = wkey[it & 1][1];
    unsigned long long k2 = wkey[it & 1][2];
    unsigned long long k3 = wkey[it & 1][3];
    unsigned long long m01 = (k1 > k0) ? k1 : k0;
    unsigned long long m23 = (k3 > k2) ? k3 : k2;
    unsigned long long mm = (m23 > m01) ? m23 : m01;
    cur = 0x7FFFFFFF - (int)(unsigned)mm;
  }
}

// ---------------------------------------------------------------------------
// KNN (wave-per-group, no LDS, no barriers):
//  - lane owns 32 candidates n = slot*64+lane; d2 -> monotonic sortable u32 key
//  - 32x: butterfly u64-min of ((key<<32)|n) (ties -> smallest n, matches
//    top_k / argmin first-index), owner lane invalidates + rescans registers
//  - output SET of indices + sel[0] is exactly the reference's; downstream
//    (pooling, std) is order-invariant so extraction order is free.
//  - diff + fp64 std partial sums fused (f64 butterfly + 2 atomics/wave).
// d2 arithmetic bit-identical to ref: (aa+bb) - 2*dot, pairwise assoc.
// ---------------------------------------------------------------------------
__global__ __launch_bounds__(256) void knn_kernel(const float* __restrict__ points,
                                                  const float* __restrict__ centers,
                                                  int* __restrict__ knn, int* __restrict__ cidx,
                                                  float* __restrict__ diffb,
                                                  double* __restrict__ sums) {
  const int t = threadIdx.x;
  const int w = t >> 6, lane = t & 63;
  const int bg = blockIdx.x * 4 + w;
  const int b = bg >> 9;

  const float* P = points + (size_t)b * Nn * 3;
  const float* cc = centers + (size_t)bg * 3;
  const float cx = cc[0], cy = cc[1], cz = cc[2];
  const float aa = __fadd_rn(__fadd_rn(__fmul_rn(cx, cx), __fmul_rn(cy, cy)), __fmul_rn(cz, cz));

  unsigned key[32];
#pragma unroll 8
  for (int s = 0; s < 32; ++s) {
    const int n = s * 64 + lane;
    float X = P[n * 3], Y = P[n * 3 + 1], Z = P[n * 3 + 2];
    float bbv = __fadd_rn(__fadd_rn(__fmul_rn(X, X), __fmul_rn(Y, Y)), __fmul_rn(Z, Z));
    float dot = __fadd_rn(__fadd_rn(__fmul_rn(cx, X), __fmul_rn(cy, Y)), __fmul_rn(cz, Z));
    float d2 = __fsub_rn(__fadd_rn(aa, bbv), __fmul_rn(2.0f, dot));
    unsigned u = __float_as_uint(d2);
    key[s] = u ^ ((unsigned)((int)u >> 31) | 0x80000000u);   // monotonic float->u32
  }

  // initial local (minkey, minslot): smallest slot wins ties (== smallest n)
  unsigned mk = key[0]; int ms = 0;
#pragma unroll
  for (int s = 1; s < 32; ++s)
    if (key[s] < mk) { mk = key[s]; ms = s; }

  int mysel = 0;
  for (int it = 0; it < Sn; ++it) {
    unsigned long long p = ((unsigned long long)mk << 32) | (unsigned)(ms * 64 + lane);
#pragma unroll
    for (int off = 1; off <= 32; off <<= 1) {
      unsigned long long o = __shfl_xor(p, off, 64);
      p = (o < p) ? o : p;
    }
    const int n_win = (int)(unsigned)p;
    if (lane == it) mysel = n_win;
    if (lane == (n_win & 63)) {           // owner: invalidate + rescan registers
      const int sw = n_win >> 6;
#pragma unroll
      for (int s = 0; s < 32; ++s)
        if (s == sw) key[s] = 0xFFFFFFFFu;
      mk = key[0]; ms = 0;
#pragma unroll
      for (int s = 1; s < 32; ++s)
        if (key[s] < mk) { mk = key[s]; ms = s; }
    }
  }

  double s1 = 0.0, s2 = 0.0;
  if (lane < Sn) {
    knn[(size_t)bg * Sn + lane] = mysel;
    float X = P[mysel * 3], Y = P[mysel * 3 + 1], Z = P[mysel * 3 + 2];
    float dx = __fsub_rn(X, cx), dy = __fsub_rn(Y, cy), dz = __fsub_rn(Z, cz);
    float* db = diffb + (size_t)bg * 96 + lane * 3;
    db[0] = dx; db[1] = dy; db[2] = dz;
    s1 = (double)dx + (double)dy + (double)dz;
    s2 = (double)dx * (double)dx + (double)dy * (double)dy + (double)dz * (double)dz;
  }
#pragma unroll
  for (int off = 1; off <= 32; off <<= 1) {
    s1 += __shfl_xor(s1, off, 64);
    s2 += __shfl_xor(s2, off, 64);
  }
  if (lane == 0) {
    cidx[bg] = __shfl(mysel, 0, 64);   // it==0 winner == argmin(d2), first-idx ties
    atomicAdd(sums, s1);
    atomicAdd(sums + 1, s2);
  }
}

// ---------------------------------------------------------------------------
// Global std (unbiased) from fp64 sums
// ---------------------------------------------------------------------------
__global__ void stddev_kernel(const double* __restrict__ sums, float* __restrict__ stdp) {
  const double n = (double)(Bn * Gn * Sn * 3);
  double s1 = sums[0], s2 = sums[1];
  double mean = s1 / n;
  double var = (s2 - s1 * mean) / (n - 1.0);
  *stdp = (float)sqrt(var) + 1e-5f;
}

// ---------------------------------------------------------------------------
// GEMM1: X(gathered 2D concat) @ W1^T, +b1, ReLU, fused Fourier pos-embed
// epilogue: G1 = (y+pos)*pos -> bf16. 64x64 tile, 4 waves, 16x16x32 mfma.
// ---------------------------------------------------------------------------
__global__ __launch_bounds__(256) void gemm1_kernel(
    const float* __restrict__ feats, const unsigned short* __restrict__ W1b,
    const float* __restrict__ b1, const int* __restrict__ knn,
    const int* __restrict__ cidx, const float* __restrict__ diffb,
    const float* __restrict__ stdp_p, const float* __restrict__ denomTab,
    unsigned short* __restrict__ G1) {
  __shared__ unsigned short As[64 * 40];   // +8 bf16 pad: 2-way-free LDS banks
  __shared__ unsigned short Bs[64 * 40];
  const int t = threadIdx.x;
  const int bm = blockIdx.x, bn = blockIdx.y;
  const int wid = t >> 6, lane = t & 63, quad = lane >> 4, c16 = lane & 15;
  const int sr = t >> 2, sseg = t & 3;

  const int grow = bm * 64 + sr;
  const int bg = grow >> 5, s = grow & 31;
  const int b = bg >> 9;
  const int nidx = knn[(size_t)bg * Sn + s];
  const int ci = cidx[bg];
  const float* baseN = feats + ((size_t)(b * Nn + nidx)) * Dn;
  const float* baseC = feats + ((size_t)(b * Nn + ci)) * Dn;
  const unsigned short* wrow = W1b + (size_t)(bn * 64 + sr) * 384;

  floatx4 acc[4];
#pragma unroll
  for (int i = 0; i < 4; ++i) acc[i] = (floatx4){0.f, 0.f, 0.f, 0.f};

  for (int kt = 0; kt < 12; ++kt) {
    const int kb = kt * 32 + sseg * 8;
    const float* src = (kb < Dn) ? (baseN + kb) : (baseC + (kb - Dn));
    const float4* s4 = reinterpret_cast<const float4*>(src);
    float4 f0 = s4[0], f1 = s4[1];
    ushortx8 av;
    av[0] = f2bf(f0.x); av[1] = f2bf(f0.y); av[2] = f2bf(f0.z); av[3] = f2bf(f0.w);
    av[4] = f2bf(f1.x); av[5] = f2bf(f1.y); av[6] = f2bf(f1.z); av[7] = f2bf(f1.w);
    ushortx8 bv = *reinterpret_cast<const ushortx8*>(wrow + kt * 32 + sseg * 8);
    __syncthreads();
    *reinterpret_cast<ushortx8*>(&As[sr * 40 + sseg * 8]) = av;
    *reinterpret_cast<ushortx8*>(&Bs[sr * 40 + sseg * 8]) = bv;
    __syncthreads();
    ushortx8 bfrag = *reinterpret_cast<const ushortx8*>(&Bs[(wid * 16 + c16) * 40 + quad * 8]);
#pragma unroll
    for (int mt = 0; mt < 4; ++mt) {
      ushortx8 afrag = *reinterpret_cast<const ushortx8*>(&As[(mt * 16 + c16) * 40 + quad * 8]);
      acc[mt] = mfma_bf16(afrag, bfrag, acc[mt]);
    }
  }

  const int col = bn * 64 + wid * 16 + c16;
  const float bias = b1[col];
  const int i3 = col >> 7;
  const int j = col & 127;
  const int jj = j & 63;
  const bool use_sin = (j < 64);
  const float dnm = denomTab[jj];
  const float stdp = *stdp_p;
#pragma unroll
  for (int mt = 0; mt < 4; ++mt) {
#pragma unroll
    for (int r = 0; r < 4; ++r) {
      const int row = bm * 64 + mt * 16 + quad * 4 + r;
      float y = fmaxf(acc[mt][r] + bias, 0.f);
      float dv = diffb[(size_t)row * 3 + i3];
      float x = __fdiv_rn(dv, stdp);
      float z = __fdiv_rn(__fmul_rn(100.0f, x), dnm);
      float p = use_sin ? sinf(z) : cosf(z);
      float g = (y + p) * p;
      G1[(size_t)row * 384 + col] = f2bf(g);
    }
  }
}

// ---------------------------------------------------------------------------
// GEMM2: H = relu(G1 @ Wa^T + ba)  (K=384, N=192)
// ---------------------------------------------------------------------------
__global__ __launch_bounds__(256) void gemm2_kernel(
    const unsigned short* __restrict__ G1, const unsigned short* __restrict__ Wab,
    const float* __restrict__ ba, unsigned short* __restrict__ H) {
  __shared__ unsigned short As[64 * 40];
  __shared__ unsigned short Bs[64 * 40];
  const int t = threadIdx.x;
  const int bm = blockIdx.x, bn = blockIdx.y;
  const int wid = t >> 6, lane = t & 63, quad = lane >> 4, c16 = lane & 15;
  const int sr = t >> 2, sseg = t & 3;

  const int grow = bm * 64 + sr;
  const unsigned short* arow = G1 + (size_t)grow * 384;
  const unsigned short* wrow = Wab + (size_t)(bn * 64 + sr) * 384;

  floatx4 acc[4];
#pragma unroll
  for (int i = 0; i < 4; ++i) acc[i] = (floatx4){0.f, 0.f, 0.f, 0.f};

  for (int kt = 0; kt < 12; ++kt) {
    const int kb = kt * 32 + sseg * 8;
    ushortx8 av = *reinterpret_cast<const ushortx8*>(arow + kb);
    ushortx8 bv = *reinterpret_cast<const ushortx8*>(wrow + kb);
    __syncthreads();
    *reinterpret_cast<ushortx8*>(&As[sr * 40 + sseg * 8]) = av;
    *reinterpret_cast<ushortx8*>(&Bs[sr * 40 + sseg * 8]) = bv;
    __syncthreads();
    ushortx8 bfrag = *reinterpret_cast<const ushortx8*>(&Bs[(wid * 16 + c16) * 40 + quad * 8]);
#pragma unroll
    for (int mt = 0; mt < 4; ++mt) {
      ushortx8 afrag = *reinterpret_cast<const ushortx8*>(&As[(mt * 16 + c16) * 40 + quad * 8]);
      acc[mt] = mfma_bf16(afrag, bfrag, acc[mt]);
    }
  }

  const int col = bn * 64 + wid * 16 + c16;   // < 192
  const float bias = ba[col];
#pragma unroll
  for (int mt = 0; mt < 4; ++mt) {
#pragma unroll
    for (int r = 0; r < 4; ++r) {
      const int row = bm * 64 + mt * 16 + quad * 4 + r;
      float h = fmaxf(acc[mt][r] + bias, 0.f);
      H[(size_t)row * 192 + col] = f2bf(h);
    }
  }
}

// ---------------------------------------------------------------------------
// GEMM3: relu(H @ Wb^T + bb + G1) then fused max+mean pooling over S=32 rows.
// 64-row tile = 2 groups; cross-quad shfl_xor reduction; writes d_out directly.
// ---------------------------------------------------------------------------
__global__ __launch_bounds__(256) void gemm3_kernel(
    const unsigned short* __restrict__ H, const unsigned short* __restrict__ Wbb,
    const float* __restrict__ bb, const unsigned short* __restrict__ G1,
    float* __restrict__ outp) {
  __shared__ unsigned short As[64 * 40];
  __shared__ unsigned short Bs[64 * 40];
  const int t = threadIdx.x;
  const int bm = blockIdx.x, bn = blockIdx.y;
  const int wid = t >> 6, lane = t & 63, quad = lane >> 4, c16 = lane & 15;
  const int sr = t >> 2, sseg = t & 3;

  const int grow = bm * 64 + sr;
  const unsigned short* arow = H + (size_t)grow * 192;
  const unsigned short* wrow = Wbb + (size_t)(bn * 64 + sr) * 192;

  floatx4 acc[4];
#pragma unroll
  for (int i = 0; i < 4; ++i) acc[i] = (floatx4){0.f, 0.f, 0.f, 0.f};

  for (int kt = 0; kt < 6; ++kt) {
    const int kb = kt * 32 + sseg * 8;
    ushortx8 av = *reinterpret_cast<const ushortx8*>(arow + kb);
    ushortx8 bv = *reinterpret_cast<const ushortx8*>(wrow + kb);
    __syncthreads();
    *reinterpret_cast<ushortx8*>(&As[sr * 40 + sseg * 8]) = av;
    *reinterpret_cast<ushortx8*>(&Bs[sr * 40 + sseg * 8]) = bv;
    __syncthreads();
    ushortx8 bfrag = *reinterpret_cast<const ushortx8*>(&Bs[(wid * 16 + c16) * 40 + quad * 8]);
#pragma unroll
    for (int mt = 0; mt < 4; ++mt) {
      ushortx8 afrag = *reinterpret_cast<const ushortx8*>(&As[(mt * 16 + c16) * 40 + quad * 8]);
      acc[mt] = mfma_bf16(afrag, bfrag, acc[mt]);
    }
  }

  const int col = bn * 64 + wid * 16 + c16;
  const float bias = bb[col];
  float gmax[2] = {-INFINITY, -INFINITY};
  float gsum[2] = {0.f, 0.f};
#pragma unroll
  for (int mt = 0; mt < 4; ++mt) {
    const int grp = mt >> 1;
#pragma unroll
    for (int r = 0; r < 4; ++r) {
      const int row = bm * 64 + mt * 16 + quad * 4 + r;
      float v = acc[mt][r] + bias + bf2f(G1[(size_t)row * 384 + col]);
      v = fmaxf(v, 0.f);
      gmax[grp] = fmaxf(gmax[grp], v);
      gsum[grp] += v;
    }
  }
#pragma unroll
  for (int grp = 0; grp < 2; ++grp) {
    float m = gmax[grp], su = gsum[grp];
#pragma unroll
    for (int off = 16; off <= 32; off <<= 1) {
      m = fmaxf(m, __shfl_xor(m, off, 64));
      su += __shfl_xor(su, off, 64);
    }
    if (quad == 0) {
      const int bg = bm * 2 + grp;
      outp[(size_t)bg * 384 + col] = m + su / 32.0f;
    }
  }
}

// ---------------------------------------------------------------------------
extern "C" void kernel_launch(void* const* d_in, const int* in_sizes, int n_in,
                              void* d_out, int out_size, void* d_ws, size_t ws_size,
                              hipStream_t stream) {
  const float* points = (const float*)d_in[0];
  const float* feats  = (const float*)d_in[1];
  const float* W1 = (const float*)d_in[2];
  const float* b1 = (const float*)d_in[3];
  const float* Wa = (const float*)d_in[4];
  const float* ba = (const float*)d_in[5];
  const float* Wb = (const float*)d_in[6];
  const float* bb = (const float*)d_in[7];
  float* outF = (float*)d_out;

  char* ws = (char*)d_ws;
  int*            knn      = (int*)(ws + OFF_KNN);
  int*            cidx     = (int*)(ws + OFF_CIDX);
  float*          diffb    = (float*)(ws + OFF_DIFF);
  double*         sums     = (double*)(ws + OFF_SUMS);
  float*          stdp     = (float*)(ws + OFF_STD);
  float*          denomTab = (float*)(ws + OFF_DENOM);
  unsigned short* W1b      = (unsigned short*)(ws + OFF_W1B);
  unsigned short* Wab      = (unsigned short*)(ws + OFF_WAB);
  unsigned short* Wbb      = (unsigned short*)(ws + OFF_WBB);
  unsigned short* G1       = (unsigned short*)(ws + OFF_G1);
  unsigned short* H        = (unsigned short*)(ws + OFF_H);

  hipMemsetAsync(sums, 0, 2 * sizeof(double), stream);
  prep_kernel<<<1152, 256, 0, stream>>>(W1, Wa, Wb, W1b, Wab, Wbb, denomTab);
  fps_kernel<<<Bn, 256, 0, stream>>>(points, outF);
  knn_kernel<<<Bn * Gn / 4, 256, 0, stream>>>(points, outF, knn, cidx, diffb, sums);
  stddev_kernel<<<1, 1, 0, stream>>>(sums, stdp);
  gemm1_kernel<<<dim3(Mrows / 64, 6), 256, 0, stream>>>(feats, W1b, b1, knn, cidx,
                                                        diffb, stdp, denomTab, G1);
  gemm2_kernel<<<dim3(Mrows / 64, 3), 256, 0, stream>>>(G1, Wab, ba, H);
  gemm3_kernel<<<dim3(Mrows / 64, 6), 256, 0, stream>>>(H, Wbb, bb, G1, outF + Bn * Gn * 3);
}

// Round 5
// 680.029 us; speedup vs baseline: 1.8030x; 1.1364x over previous
//
#include <hip/hip_runtime.h>
#include <math.h>

// Problem constants
#define Bn   8
#define Nn   2048
#define Dn   192
#define Gn   512
#define Sn   32
#define OUTn 384
#define Mrows (Bn * Gn * Sn)   // 131072 rows through the MLP

typedef __attribute__((ext_vector_type(8))) unsigned short ushortx8;
typedef __attribute__((ext_vector_type(8))) __bf16 bf16x8;
typedef __attribute__((ext_vector_type(4))) float floatx4;

// ---------- ws layout (bytes) ----------
static constexpr size_t OFF_KNN   = 0;                    // 131072 * 4
static constexpr size_t OFF_CIDX  = 524288;               // 4096 * 4
static constexpr size_t OFF_DIFF  = 540672;               // 393216 * 4
static constexpr size_t OFF_SUMS  = 2113536;              // 2 doubles
static constexpr size_t OFF_STD   = 2113552;              // 1 float
static constexpr size_t OFF_DENOM = 2113792;              // 64 floats
static constexpr size_t OFF_W1B   = 2114048;              // 147456 * 2
static constexpr size_t OFF_WAB   = 2408960;              // 73728 * 2
static constexpr size_t OFF_WBB   = 2556416;              // 73728 * 2
static constexpr size_t OFF_G1    = 2703872;              // 50331648 * 2
static constexpr size_t OFF_H     = 103367168;            // 25165824 * 2
// total ~153.7 MB

__device__ __forceinline__ unsigned short f2bf(float f) {
  unsigned u = __float_as_uint(f);
  unsigned r = (u + 0x7FFFu + ((u >> 16) & 1u)) >> 16;   // RNE
  return (unsigned short)r;
}
__device__ __forceinline__ float bf2f(unsigned short h) {
  return __uint_as_float(((unsigned)h) << 16);
}
__device__ __forceinline__ floatx4 mfma_bf16(ushortx8 a, ushortx8 b, floatx4 c) {
  return __builtin_amdgcn_mfma_f32_16x16x32_bf16(
      __builtin_bit_cast(bf16x8, a), __builtin_bit_cast(bf16x8, b), c, 0, 0, 0);
}

// DPP max step: pure-VALU cross-lane (no LDS pipe). CTRL must be an ICE ->
// template parameter (runtime arg fails the builtin's constant check).
// bound_ctrl=1 -> 0-fill, the max-identity for our nonneg distances.
template <int CTRL>
__device__ __forceinline__ float dpp_max(float v) {
  int o = __builtin_amdgcn_update_dpp(0, __float_as_int(v), CTRL, 0xf, 0xf, true);
  return fmaxf(v, __int_as_float(o));
}

// ---------------------------------------------------------------------------
// prep: fp32 weights -> bf16, and Fourier denom table
// ---------------------------------------------------------------------------
__global__ void prep_kernel(const float* __restrict__ W1, const float* __restrict__ Wa,
                            const float* __restrict__ Wb,
                            unsigned short* __restrict__ W1b, unsigned short* __restrict__ Wab,
                            unsigned short* __restrict__ Wbb, float* __restrict__ denomTab) {
  int i = blockIdx.x * 256 + threadIdx.x;
  if (i < 147456)            W1b[i] = f2bf(W1[i]);
  else if (i < 221184)       Wab[i - 147456] = f2bf(Wa[i - 147456]);
  else if (i < 294912)       Wbb[i - 221184] = f2bf(Wb[i - 221184]);
  if (blockIdx.x == 0 && threadIdx.x < 64)
    denomTab[threadIdx.x] = (float)pow(1000.0, (double)threadIdx.x / 64.0);
}

// ---------------------------------------------------------------------------
// FPS (DPP-argmax): one block (4 waves) per batch, LANE-MAJOR ownership
// n = t*8+k so that "lowest tied lane" == "smallest global index".
// Per iter: value-only local max -> 6-step DPP wave max (VALU) -> scalar
// resolution (readlane M, ballot, ffs, readlane li) -> u64 cross-wave key.
// Distance arithmetic bit-identical to numpy ref (no FMA contraction);
// argmax first-index tie-break preserved exactly.
// ---------------------------------------------------------------------------
__global__ __launch_bounds__(256) void fps_kernel(const float* __restrict__ points,
                                                  float* __restrict__ centers) {
  const int b = blockIdx.x;
  const int t = threadIdx.x;
  const int w = t >> 6, lane = t & 63;
  __shared__ float4 p4[Nn];
  __shared__ unsigned long long wkey[2][4];

  const float* P = points + (size_t)b * Nn * 3;
  for (int n = t; n < Nn; n += 256) {
    float x = P[n * 3], y = P[n * 3 + 1], z = P[n * 3 + 2];
    p4[n] = make_float4(x, y, z, 0.f);
  }
  __syncthreads();

  float rx[8], ry[8], rz[8], dist[8];
#pragma unroll
  for (int k = 0; k < 8; ++k) {
    float4 p = p4[t * 8 + k];       // lane-major: one-time conflict, ok
    rx[k] = p.x; ry[k] = p.y; rz[k] = p.z;
    dist[k] = INFINITY;
  }

  int cur = 0;
  for (int it = 0; it < Gn; ++it) {
    const float4 c = p4[cur];
    if (t == 0) {
      float* cd = centers + ((size_t)b * Gn + it) * 3;
      cd[0] = c.x; cd[1] = c.y; cd[2] = c.z;
    }
    // update dists + local max VALUE only
    float bv = -1.0f;
#pragma unroll
    for (int k = 0; k < 8; ++k) {
      float dx = __fsub_rn(rx[k], c.x);
      float dy = __fsub_rn(ry[k], c.y);
      float dz = __fsub_rn(rz[k], c.z);
      float d = __fadd_rn(__fadd_rn(__fmul_rn(dx, dx), __fmul_rn(dy, dy)), __fmul_rn(dz, dz));
      dist[k] = fminf(dist[k], d);
      bv = fmaxf(bv, dist[k]);
    }
    // local first-index among ties: descending scan ends at smallest k
    int li = 7;
#pragma unroll
    for (int k = 6; k >= 0; --k) li = (dist[k] == bv) ? k : li;

    // wave max via DPP (result valid in lane 63)
    float red = bv;
    red = dpp_max<0x111>(red);   // row_shr:1
    red = dpp_max<0x112>(red);   // row_shr:2
    red = dpp_max<0x114>(red);   // row_shr:4
    red = dpp_max<0x118>(red);   // row_shr:8
    red = dpp_max<0x142>(red);   // row_bcast:15
    red = dpp_max<0x143>(red);   // row_bcast:31
    const float M = __int_as_float(__builtin_amdgcn_readlane(__float_as_int(red), 63));

    // scalar argmax resolution: first tied lane holds the smallest global idx
    unsigned long long msk = __ballot(bv == M);
    const int L = __ffsll((long long)msk) - 1;
    const int liL = __builtin_amdgcn_readlane(li, L);
    const int idx = (w * 64 + L) * 8 + liL;

    unsigned long long key =
        ((unsigned long long)__float_as_uint(M) << 32) | (unsigned)(0x7FFFFFFF - idx);
    if (lane == 0) wkey[it & 1][w] = key;
    __syncthreads();
    unsigned long long k0 = wkey[it & 1][0];
    unsigned long long k1 = wkey[it & 1][1];
    unsigned long long k2 = wkey[it & 1][2];
    unsigned long long k3 = wkey[it & 1][3];
    unsigned long long m01 = (k1 > k0) ? k1 : k0;
    unsigned long long m23 = (k3 > k2) ? k3 : k2;
    unsigned long long mm = (m23 > m01) ? m23 : m01;
    cur = 0x7FFFFFFF - (int)(unsigned)mm;
  }
}

// ---------------------------------------------------------------------------
// KNN (wave-per-group, no LDS, no barriers):
//  - lane owns 32 candidates n = slot*64+lane; d2 -> monotonic sortable u32 key
//  - 32x: butterfly u64-min of ((key<<32)|n) (ties -> smallest n, matches
//    top_k / argmin first-index), owner lane invalidates + rescans registers
//  - diff + fp64 std partial sums fused (f64 butterfly + 2 atomics/wave).
// d2 arithmetic bit-identical to ref: (aa+bb) - 2*dot, pairwise assoc.
// ---------------------------------------------------------------------------
__global__ __launch_bounds__(256) void knn_kernel(const float* __restrict__ points,
                                                  const float* __restrict__ centers,
                                                  int* __restrict__ knn, int* __restrict__ cidx,
                                                  float* __restrict__ diffb,
                                                  double* __restrict__ sums) {
  const int t = threadIdx.x;
  const int w = t >> 6, lane = t & 63;
  const int bg = blockIdx.x * 4 + w;
  const int b = bg >> 9;

  const float* P = points + (size_t)b * Nn * 3;
  const float* cc = centers + (size_t)bg * 3;
  const float cx = cc[0], cy = cc[1], cz = cc[2];
  const float aa = __fadd_rn(__fadd_rn(__fmul_rn(cx, cx), __fmul_rn(cy, cy)), __fmul_rn(cz, cz));

  unsigned key[32];
#pragma unroll 8
  for (int s = 0; s < 32; ++s) {
    const int n = s * 64 + lane;
    float X = P[n * 3], Y = P[n * 3 + 1], Z = P[n * 3 + 2];
    float bbv = __fadd_rn(__fadd_rn(__fmul_rn(X, X), __fmul_rn(Y, Y)), __fmul_rn(Z, Z));
    float dot = __fadd_rn(__fadd_rn(__fmul_rn(cx, X), __fmul_rn(cy, Y)), __fmul_rn(cz, Z));
    float d2 = __fsub_rn(__fadd_rn(aa, bbv), __fmul_rn(2.0f, dot));
    unsigned u = __float_as_uint(d2);
    key[s] = u ^ ((unsigned)((int)u >> 31) | 0x80000000u);   // monotonic float->u32
  }

  // initial local (minkey, minslot): smallest slot wins ties (== smallest n)
  unsigned mk = key[0]; int ms = 0;
#pragma unroll
  for (int s = 1; s < 32; ++s)
    if (key[s] < mk) { mk = key[s]; ms = s; }

  int mysel = 0;
  for (int it = 0; it < Sn; ++it) {
    unsigned long long p = ((unsigned long long)mk << 32) | (unsigned)(ms * 64 + lane);
#pragma unroll
    for (int off = 1; off <= 32; off <<= 1) {
      unsigned long long o = __shfl_xor(p, off, 64);
      p = (o < p) ? o : p;
    }
    const int n_win = (int)(unsigned)p;
    if (lane == it) mysel = n_win;
    if (lane == (n_win & 63)) {           // owner: invalidate + rescan registers
      const int sw = n_win >> 6;
#pragma unroll
      for (int s = 0; s < 32; ++s)
        if (s == sw) key[s] = 0xFFFFFFFFu;
      mk = key[0]; ms = 0;
#pragma unroll
      for (int s = 1; s < 32; ++s)
        if (key[s] < mk) { mk = key[s]; ms = s; }
    }
  }

  double s1 = 0.0, s2 = 0.0;
  if (lane < Sn) {
    knn[(size_t)bg * Sn + lane] = mysel;
    float X = P[mysel * 3], Y = P[mysel * 3 + 1], Z = P[mysel * 3 + 2];
    float dx = __fsub_rn(X, cx), dy = __fsub_rn(Y, cy), dz = __fsub_rn(Z, cz);
    float* db = diffb + (size_t)bg * 96 + lane * 3;
    db[0] = dx; db[1] = dy; db[2] = dz;
    s1 = (double)dx + (double)dy + (double)dz;
    s2 = (double)dx * (double)dx + (double)dy * (double)dy + (double)dz * (double)dz;
  }
#pragma unroll
  for (int off = 1; off <= 32; off <<= 1) {
    s1 += __shfl_xor(s1, off, 64);
    s2 += __shfl_xor(s2, off, 64);
  }
  if (lane == 0) {
    cidx[bg] = __shfl(mysel, 0, 64);   // it==0 winner == argmin(d2), first-idx ties
    atomicAdd(sums, s1);
    atomicAdd(sums + 1, s2);
  }
}

// ---------------------------------------------------------------------------
// Global std (unbiased) from fp64 sums
// ---------------------------------------------------------------------------
__global__ void stddev_kernel(const double* __restrict__ sums, float* __restrict__ stdp) {
  const double n = (double)(Bn * Gn * Sn * 3);
  double s1 = sums[0], s2 = sums[1];
  double mean = s1 / n;
  double var = (s2 - s1 * mean) / (n - 1.0);
  *stdp = (float)sqrt(var) + 1e-5f;
}

// ---------------------------------------------------------------------------
// GEMM1: X(gathered 2D concat) @ W1^T, +b1, ReLU, fused Fourier pos-embed
// epilogue: G1 = (y+pos)*pos -> bf16. 64x64 tile, 4 waves, 16x16x32 mfma.
// ---------------------------------------------------------------------------
__global__ __launch_bounds__(256) void gemm1_kernel(
    const float* __restrict__ feats, const unsigned short* __restrict__ W1b,
    const float* __restrict__ b1, const int* __restrict__ knn,
    const int* __restrict__ cidx, const float* __restrict__ diffb,
    const float* __restrict__ stdp_p, const float* __restrict__ denomTab,
    unsigned short* __restrict__ G1) {
  __shared__ unsigned short As[64 * 40];   // +8 bf16 pad: 2-way-free LDS banks
  __shared__ unsigned short Bs[64 * 40];
  const int t = threadIdx.x;
  const int bm = blockIdx.x, bn = blockIdx.y;
  const int wid = t >> 6, lane = t & 63, quad = lane >> 4, c16 = lane & 15;
  const int sr = t >> 2, sseg = t & 3;

  const int grow = bm * 64 + sr;
  const int bg = grow >> 5, s = grow & 31;
  const int b = bg >> 9;
  const int nidx = knn[(size_t)bg * Sn + s];
  const int ci = cidx[bg];
  const float* baseN = feats + ((size_t)(b * Nn + nidx)) * Dn;
  const float* baseC = feats + ((size_t)(b * Nn + ci)) * Dn;
  const unsigned short* wrow = W1b + (size_t)(bn * 64 + sr) * 384;

  floatx4 acc[4];
#pragma unroll
  for (int i = 0; i < 4; ++i) acc[i] = (floatx4){0.f, 0.f, 0.f, 0.f};

  for (int kt = 0; kt < 12; ++kt) {
    const int kb = kt * 32 + sseg * 8;
    const float* src = (kb < Dn) ? (baseN + kb) : (baseC + (kb - Dn));
    const float4* s4 = reinterpret_cast<const float4*>(src);
    float4 f0 = s4[0], f1 = s4[1];
    ushortx8 av;
    av[0] = f2bf(f0.x); av[1] = f2bf(f0.y); av[2] = f2bf(f0.z); av[3] = f2bf(f0.w);
    av[4] = f2bf(f1.x); av[5] = f2bf(f1.y); av[6] = f2bf(f1.z); av[7] = f2bf(f1.w);
    ushortx8 bv = *reinterpret_cast<const ushortx8*>(wrow + kt * 32 + sseg * 8);
    __syncthreads();
    *reinterpret_cast<ushortx8*>(&As[sr * 40 + sseg * 8]) = av;
    *reinterpret_cast<ushortx8*>(&Bs[sr * 40 + sseg * 8]) = bv;
    __syncthreads();
    ushortx8 bfrag = *reinterpret_cast<const ushortx8*>(&Bs[(wid * 16 + c16) * 40 + quad * 8]);
#pragma unroll
    for (int mt = 0; mt < 4; ++mt) {
      ushortx8 afrag = *reinterpret_cast<const ushortx8*>(&As[(mt * 16 + c16) * 40 + quad * 8]);
      acc[mt] = mfma_bf16(afrag, bfrag, acc[mt]);
    }
  }

  const int col = bn * 64 + wid * 16 + c16;
  const float bias = b1[col];
  const int i3 = col >> 7;
  const int j = col & 127;
  const int jj = j & 63;
  const bool use_sin = (j < 64);
  const float dnm = denomTab[jj];
  const float stdp = *stdp_p;
#pragma unroll
  for (int mt = 0; mt < 4; ++mt) {
#pragma unroll
    for (int r = 0; r < 4; ++r) {
      const int row = bm * 64 + mt * 16 + quad * 4 + r;
      float y = fmaxf(acc[mt][r] + bias, 0.f);
      float dv = diffb[(size_t)row * 3 + i3];
      float x = __fdiv_rn(dv, stdp);
      float z = __fdiv_rn(__fmul_rn(100.0f, x), dnm);
      float p = use_sin ? sinf(z) : cosf(z);
      float g = (y + p) * p;
      G1[(size_t)row * 384 + col] = f2bf(g);
    }
  }
}

// ---------------------------------------------------------------------------
// GEMM2: H = relu(G1 @ Wa^T + ba)  (K=384, N=192)
// ---------------------------------------------------------------------------
__global__ __launch_bounds__(256) void gemm2_kernel(
    const unsigned short* __restrict__ G1, const unsigned short* __restrict__ Wab,
    const float* __restrict__ ba, unsigned short* __restrict__ H) {
  __shared__ unsigned short As[64 * 40];
  __shared__ unsigned short Bs[64 * 40];
  const int t = threadIdx.x;
  const int bm = blockIdx.x, bn = blockIdx.y;
  const int wid = t >> 6, lane = t & 63, quad = lane >> 4, c16 = lane & 15;
  const int sr = t >> 2, sseg = t & 3;

  const int grow = bm * 64 + sr;
  const unsigned short* arow = G1 + (size_t)grow * 384;
  const unsigned short* wrow = Wab + (size_t)(bn * 64 + sr) * 384;

  floatx4 acc[4];
#pragma unroll
  for (int i = 0; i < 4; ++i) acc[i] = (floatx4){0.f, 0.f, 0.f, 0.f};

  for (int kt = 0; kt < 12; ++kt) {
    const int kb = kt * 32 + sseg * 8;
    ushortx8 av = *reinterpret_cast<const ushortx8*>(arow + kb);
    ushortx8 bv = *reinterpret_cast<const ushortx8*>(wrow + kb);
    __syncthreads();
    *reinterpret_cast<ushortx8*>(&As[sr * 40 + sseg * 8]) = av;
    *reinterpret_cast<ushortx8*>(&Bs[sr * 40 + sseg * 8]) = bv;
    __syncthreads();
    ushortx8 bfrag = *reinterpret_cast<const ushortx8*>(&Bs[(wid * 16 + c16) * 40 + quad * 8]);
#pragma unroll
    for (int mt = 0; mt < 4; ++mt) {
      ushortx8 afrag = *reinterpret_cast<const ushortx8*>(&As[(mt * 16 + c16) * 40 + quad * 8]);
      acc[mt] = mfma_bf16(afrag, bfrag, acc[mt]);
    }
  }

  const int col = bn * 64 + wid * 16 + c16;   // < 192
  const float bias = ba[col];
#pragma unroll
  for (int mt = 0; mt < 4; ++mt) {
#pragma unroll
    for (int r = 0; r < 4; ++r) {
      const int row = bm * 64 + mt * 16 + quad * 4 + r;
      float h = fmaxf(acc[mt][r] + bias, 0.f);
      H[(size_t)row * 192 + col] = f2bf(h);
    }
  }
}

// ---------------------------------------------------------------------------
// GEMM3: relu(H @ Wb^T + bb + G1) then fused max+mean pooling over S=32 rows.
// 64-row tile = 2 groups; cross-quad shfl_xor reduction; writes d_out directly.
// ---------------------------------------------------------------------------
__global__ __launch_bounds__(256) void gemm3_kernel(
    const unsigned short* __restrict__ H, const unsigned short* __restrict__ Wbb,
    const float* __restrict__ bb, const unsigned short* __restrict__ G1,
    float* __restrict__ outp) {
  __shared__ unsigned short As[64 * 40];
  __shared__ unsigned short Bs[64 * 40];
  const int t = threadIdx.x;
  const int bm = blockIdx.x, bn = blockIdx.y;
  const int wid = t >> 6, lane = t & 63, quad = lane >> 4, c16 = lane & 15;
  const int sr = t >> 2, sseg = t & 3;

  const int grow = bm * 64 + sr;
  const unsigned short* arow = H + (size_t)grow * 192;
  const unsigned short* wrow = Wbb + (size_t)(bn * 64 + sr) * 192;

  floatx4 acc[4];
#pragma unroll
  for (int i = 0; i < 4; ++i) acc[i] = (floatx4){0.f, 0.f, 0.f, 0.f};

  for (int kt = 0; kt < 6; ++kt) {
    const int kb = kt * 32 + sseg * 8;
    ushortx8 av = *reinterpret_cast<const ushortx8*>(arow + kb);
    ushortx8 bv = *reinterpret_cast<const ushortx8*>(wrow + kb);
    __syncthreads();
    *reinterpret_cast<ushortx8*>(&As[sr * 40 + sseg * 8]) = av;
    *reinterpret_cast<ushortx8*>(&Bs[sr * 40 + sseg * 8]) = bv;
    __syncthreads();
    ushortx8 bfrag = *reinterpret_cast<const ushortx8*>(&Bs[(wid * 16 + c16) * 40 + quad * 8]);
#pragma unroll
    for (int mt = 0; mt < 4; ++mt) {
      ushortx8 afrag = *reinterpret_cast<const ushortx8*>(&As[(mt * 16 + c16) * 40 + quad * 8]);
      acc[mt] = mfma_bf16(afrag, bfrag, acc[mt]);
    }
  }

  const int col = bn * 64 + wid * 16 + c16;
  const float bias = bb[col];
  float gmax[2] = {-INFINITY, -INFINITY};
  float gsum[2] = {0.f, 0.f};
#pragma unroll
  for (int mt = 0; mt < 4; ++mt) {
    const int grp = mt >> 1;
#pragma unroll
    for (int r = 0; r < 4; ++r) {
      const int row = bm * 64 + mt * 16 + quad * 4 + r;
      float v = acc[mt][r] + bias + bf2f(G1[(size_t)row * 384 + col]);
      v = fmaxf(v, 0.f);
      gmax[grp] = fmaxf(gmax[grp], v);
      gsum[grp] += v;
    }
  }
#pragma unroll
  for (int grp = 0; grp < 2; ++grp) {
    float m = gmax[grp], su = gsum[grp];
#pragma unroll
    for (int off = 16; off <= 32; off <<= 1) {
      m = fmaxf(m, __shfl_xor(m, off, 64));
      su += __shfl_xor(su, off, 64);
    }
    if (quad == 0) {
      const int bg = bm * 2 + grp;
      outp[(size_t)bg * 384 + col] = m + su / 32.0f;
    }
  }
}

// ---------------------------------------------------------------------------
extern "C" void kernel_launch(void* const* d_in, const int* in_sizes, int n_in,
                              void* d_out, int out_size, void* d_ws, size_t ws_size,
                              hipStream_t stream) {
  const float* points = (const float*)d_in[0];
  const float* feats  = (const float*)d_in[1];
  const float* W1 = (const float*)d_in[2];
  const float* b1 = (const float*)d_in[3];
  const float* Wa = (const float*)d_in[4];
  const float* ba = (const float*)d_in[5];
  const float* Wb = (const float*)d_in[6];
  const float* bb = (const float*)d_in[7];
  float* outF = (float*)d_out;

  char* ws = (char*)d_ws;
  int*            knn      = (int*)(ws + OFF_KNN);
  int*            cidx     = (int*)(ws + OFF_CIDX);
  float*          diffb    = (float*)(ws + OFF_DIFF);
  double*         sums     = (double*)(ws + OFF_SUMS);
  float*          stdp     = (float*)(ws + OFF_STD);
  float*          denomTab = (float*)(ws + OFF_DENOM);
  unsigned short* W1b      = (unsigned short*)(ws + OFF_W1B);
  unsigned short* Wab      = (unsigned short*)(ws + OFF_WAB);
  unsigned short* Wbb      = (unsigned short*)(ws + OFF_WBB);
  unsigned short* G1       = (unsigned short*)(ws + OFF_G1);
  unsigned short* H        = (unsigned short*)(ws + OFF_H);

  hipMemsetAsync(sums, 0, 2 * sizeof(double), stream);
  prep_kernel<<<1152, 256, 0, stream>>>(W1, Wa, Wb, W1b, Wab, Wbb, denomTab);
  fps_kernel<<<Bn, 256, 0, stream>>>(points, outF);
  knn_kernel<<<Bn * Gn / 4, 256, 0, stream>>>(points, outF, knn, cidx, diffb, sums);
  stddev_kernel<<<1, 1, 0, stream>>>(sums, stdp);
  gemm1_kernel<<<dim3(Mrows / 64, 6), 256, 0, stream>>>(feats, W1b, b1, knn, cidx,
                                                        diffb, stdp, denomTab, G1);
  gemm2_kernel<<<dim3(Mrows / 64, 3), 256, 0, stream>>>(G1, Wab, ba, H);
  gemm3_kernel<<<dim3(Mrows / 64, 6), 256, 0, stream>>>(H, Wbb, bb, G1, outF + Bn * Gn * 3);
}

// Round 6
// 612.837 us; speedup vs baseline: 2.0007x; 1.1096x over previous
//
#include <hip/hip_runtime.h>
#include <math.h>

// Problem constants
#define Bn   8
#define Nn   2048
#define Dn   192
#define Gn   512
#define Sn   32
#define OUTn 384
#define Mrows (Bn * Gn * Sn)   // 131072 rows through the MLP

typedef __attribute__((ext_vector_type(8))) unsigned short ushortx8;
typedef __attribute__((ext_vector_type(8))) __bf16 bf16x8;
typedef __attribute__((ext_vector_type(4))) float floatx4;

// ---------- ws layout (bytes) ----------
static constexpr size_t OFF_KNN   = 0;                    // 131072 * 4
static constexpr size_t OFF_CIDX  = 524288;               // 4096 * 4
static constexpr size_t OFF_DIFF  = 540672;               // 393216 * 4
static constexpr size_t OFF_SUMS  = 2113536;              // 2 doubles
static constexpr size_t OFF_STD   = 2113552;              // 1 float (stores 1/std)
static constexpr size_t OFF_DENOM = 2113792;              // 64 floats (stores 1/denom)
static constexpr size_t OFF_W1B   = 2114048;              // 147456 * 2
static constexpr size_t OFF_WAB   = 2408960;              // 73728 * 2
static constexpr size_t OFF_WBB   = 2556416;              // 73728 * 2
static constexpr size_t OFF_G1    = 2703872;              // 50331648 * 2
static constexpr size_t OFF_H     = 103367168;            // 25165824 * 2
// featb (bf16 feats, 6.3 MB) ALIASES the H region: gemm1 reads featb, gemm2
// writes H strictly afterwards (stream-ordered) — total stays ~154 MB.
static constexpr size_t OFF_FEATB = OFF_H;

__device__ __forceinline__ unsigned short f2bf(float f) {
  unsigned u = __float_as_uint(f);
  unsigned r = (u + 0x7FFFu + ((u >> 16) & 1u)) >> 16;   // RNE
  return (unsigned short)r;
}
__device__ __forceinline__ float bf2f(unsigned short h) {
  return __uint_as_float(((unsigned)h) << 16);
}
__device__ __forceinline__ floatx4 mfma_bf16(ushortx8 a, ushortx8 b, floatx4 c) {
  return __builtin_amdgcn_mfma_f32_16x16x32_bf16(
      __builtin_bit_cast(bf16x8, a), __builtin_bit_cast(bf16x8, b), c, 0, 0, 0);
}

// async global->LDS, 16 B per lane. LDS dest = wave-uniform base + lane*16.
__device__ __forceinline__ void gld16(const void* g, void* l) {
  __builtin_amdgcn_global_load_lds(
      (const __attribute__((address_space(1))) unsigned int*)g,
      (__attribute__((address_space(3))) unsigned int*)l, 16, 0, 0);
}

template <int CTRL>
__device__ __forceinline__ float dpp_max(float v) {
  int o = __builtin_amdgcn_update_dpp(0, __float_as_int(v), CTRL, 0xf, 0xf, true);
  return fmaxf(v, __int_as_float(o));
}

// ---------------------------------------------------------------------------
// prep: weights + feats fp32 -> bf16, reciprocal Fourier denom table
// ---------------------------------------------------------------------------
__global__ void prep_kernel(const float* __restrict__ W1, const float* __restrict__ Wa,
                            const float* __restrict__ Wb, const float* __restrict__ feats,
                            unsigned short* __restrict__ W1b, unsigned short* __restrict__ Wab,
                            unsigned short* __restrict__ Wbb, unsigned short* __restrict__ featb,
                            float* __restrict__ rdenomTab) {
  int i = blockIdx.x * 256 + threadIdx.x;
  if (i < 147456)            W1b[i] = f2bf(W1[i]);
  else if (i < 221184)       Wab[i - 147456] = f2bf(Wa[i - 147456]);
  else if (i < 294912)       Wbb[i - 221184] = f2bf(Wb[i - 221184]);
  else if (i < 3440640)      featb[i - 294912] = f2bf(feats[i - 294912]);
  if (blockIdx.x == 0 && threadIdx.x < 64)
    rdenomTab[threadIdx.x] = (float)(1.0 / pow(1000.0, (double)threadIdx.x / 64.0));
}

// ---------------------------------------------------------------------------
// FPS: one block (4 waves) per batch, lane-major ownership (n = t*8+k so
// lowest tied lane == smallest global index). Points live in REGISTERS only.
// Per iter: dist update -> DPP wave max -> scalar resolve (ballot/ffs/
// readlane) -> owner xyz broadcast via readlane -> lane0 writes {key,xyz}
// -> ONE barrier -> all threads select winner record (no dependent p4 read).
// Distance math bit-identical to numpy ref; first-index ties exact.
// ---------------------------------------------------------------------------
__global__ __launch_bounds__(256) void fps_kernel(const float* __restrict__ points,
                                                  float* __restrict__ centers) {
  const int b = blockIdx.x;
  const int t = threadIdx.x;
  const int w = t >> 6, lane = t & 63;
  __shared__ unsigned long long wkey[2][4];
  __shared__ float4 wxyz[2][4];

  const float* P = points + (size_t)b * Nn * 3;
  float rx[8], ry[8], rz[8], dist[8];
#pragma unroll
  for (int k = 0; k < 8; ++k) {
    const int n = t * 8 + k;
    rx[k] = P[n * 3]; ry[k] = P[n * 3 + 1]; rz[k] = P[n * 3 + 2];
    dist[k] = INFINITY;
  }
  float cx = P[0], cy = P[1], cz = P[2];

  for (int it = 0; it < Gn; ++it) {
    if (t == 0) {
      float* cd = centers + ((size_t)b * Gn + it) * 3;
      cd[0] = cx; cd[1] = cy; cd[2] = cz;
    }
    float bv = -1.0f;
#pragma unroll
    for (int k = 0; k < 8; ++k) {
      float dx = __fsub_rn(rx[k], cx);
      float dy = __fsub_rn(ry[k], cy);
      float dz = __fsub_rn(rz[k], cz);
      float d = __fadd_rn(__fadd_rn(__fmul_rn(dx, dx), __fmul_rn(dy, dy)), __fmul_rn(dz, dz));
      dist[k] = fminf(dist[k], d);
      bv = fmaxf(bv, dist[k]);
    }
    int li = 7;
#pragma unroll
    for (int k = 6; k >= 0; --k) li = (dist[k] == bv) ? k : li;
    // candidate coords (per-lane select of its own best point)
    float sx = rx[0], sy = ry[0], sz = rz[0];
#pragma unroll
    for (int k = 1; k < 8; ++k) {
      bool p = (li == k);
      sx = p ? rx[k] : sx; sy = p ? ry[k] : sy; sz = p ? rz[k] : sz;
    }

    float red = bv;
    red = dpp_max<0x111>(red);
    red = dpp_max<0x112>(red);
    red = dpp_max<0x114>(red);
    red = dpp_max<0x118>(red);
    red = dpp_max<0x142>(red);
    red = dpp_max<0x143>(red);
    const float M = __int_as_float(__builtin_amdgcn_readlane(__float_as_int(red), 63));

    unsigned long long msk = __ballot(bv == M);
    const int L = __ffsll((long long)msk) - 1;
    const int liL = __builtin_amdgcn_readlane(li, L);
    const int idx = (w * 64 + L) * 8 + liL;
    const float wx = __int_as_float(__builtin_amdgcn_readlane(__float_as_int(sx), L));
    const float wy = __int_as_float(__builtin_amdgcn_readlane(__float_as_int(sy), L));
    const float wz = __int_as_float(__builtin_amdgcn_readlane(__float_as_int(sz), L));

    const int buf = it & 1;
    if (lane == 0) {
      wkey[buf][w] = ((unsigned long long)__float_as_uint(M) << 32) |
                     (unsigned)(0x7FFFFFFF - idx);
      wxyz[buf][w] = make_float4(wx, wy, wz, 0.f);
    }
    __syncthreads();
    unsigned long long k0 = wkey[buf][0], k1 = wkey[buf][1];
    unsigned long long k2 = wkey[buf][2], k3 = wkey[buf][3];
    float4 f0 = wxyz[buf][0], f1 = wxyz[buf][1], f2 = wxyz[buf][2], f3 = wxyz[buf][3];
    bool g01 = k1 > k0; unsigned long long m01 = g01 ? k1 : k0;
    float4 f01 = g01 ? f1 : f0;
    bool g23 = k3 > k2; unsigned long long m23 = g23 ? k3 : k2;
    float4 f23 = g23 ? f3 : f2;
    bool g = m23 > m01;
    float4 fw = g ? f23 : f01;
    cx = fw.x; cy = fw.y; cz = fw.z;
  }
}

// ---------------------------------------------------------------------------
// KNN (wave-per-group, no LDS, no barriers) — unchanged from round 5.
// ---------------------------------------------------------------------------
__global__ __launch_bounds__(256) void knn_kernel(const float* __restrict__ points,
                                                  const float* __restrict__ centers,
                                                  int* __restrict__ knn, int* __restrict__ cidx,
                                                  float* __restrict__ diffb,
                                                  double* __restrict__ sums) {
  const int t = threadIdx.x;
  const int w = t >> 6, lane = t & 63;
  const int bg = blockIdx.x * 4 + w;
  const int b = bg >> 9;

  const float* P = points + (size_t)b * Nn * 3;
  const float* cc = centers + (size_t)bg * 3;
  const float cx = cc[0], cy = cc[1], cz = cc[2];
  const float aa = __fadd_rn(__fadd_rn(__fmul_rn(cx, cx), __fmul_rn(cy, cy)), __fmul_rn(cz, cz));

  unsigned key[32];
#pragma unroll 8
  for (int s = 0; s < 32; ++s) {
    const int n = s * 64 + lane;
    float X = P[n * 3], Y = P[n * 3 + 1], Z = P[n * 3 + 2];
    float bbv = __fadd_rn(__fadd_rn(__fmul_rn(X, X), __fmul_rn(Y, Y)), __fmul_rn(Z, Z));
    float dot = __fadd_rn(__fadd_rn(__fmul_rn(cx, X), __fmul_rn(cy, Y)), __fmul_rn(cz, Z));
    float d2 = __fsub_rn(__fadd_rn(aa, bbv), __fmul_rn(2.0f, dot));
    unsigned u = __float_as_uint(d2);
    key[s] = u ^ ((unsigned)((int)u >> 31) | 0x80000000u);
  }

  unsigned mk = key[0]; int ms = 0;
#pragma unroll
  for (int s = 1; s < 32; ++s)
    if (key[s] < mk) { mk = key[s]; ms = s; }

  int mysel = 0;
  for (int it = 0; it < Sn; ++it) {
    unsigned long long p = ((unsigned long long)mk << 32) | (unsigned)(ms * 64 + lane);
#pragma unroll
    for (int off = 1; off <= 32; off <<= 1) {
      unsigned long long o = __shfl_xor(p, off, 64);
      p = (o < p) ? o : p;
    }
    const int n_win = (int)(unsigned)p;
    if (lane == it) mysel = n_win;
    if (lane == (n_win & 63)) {
      const int sw = n_win >> 6;
#pragma unroll
      for (int s = 0; s < 32; ++s)
        if (s == sw) key[s] = 0xFFFFFFFFu;
      mk = key[0]; ms = 0;
#pragma unroll
      for (int s = 1; s < 32; ++s)
        if (key[s] < mk) { mk = key[s]; ms = s; }
    }
  }

  double s1 = 0.0, s2 = 0.0;
  if (lane < Sn) {
    knn[(size_t)bg * Sn + lane] = mysel;
    float X = P[mysel * 3], Y = P[mysel * 3 + 1], Z = P[mysel * 3 + 2];
    float dx = __fsub_rn(X, cx), dy = __fsub_rn(Y, cy), dz = __fsub_rn(Z, cz);
    float* db = diffb + (size_t)bg * 96 + lane * 3;
    db[0] = dx; db[1] = dy; db[2] = dz;
    s1 = (double)dx + (double)dy + (double)dz;
    s2 = (double)dx * (double)dx + (double)dy * (double)dy + (double)dz * (double)dz;
  }
#pragma unroll
  for (int off = 1; off <= 32; off <<= 1) {
    s1 += __shfl_xor(s1, off, 64);
    s2 += __shfl_xor(s2, off, 64);
  }
  if (lane == 0) {
    cidx[bg] = __shfl(mysel, 0, 64);
    atomicAdd(sums, s1);
    atomicAdd(sums + 1, s2);
  }
}

// ---------------------------------------------------------------------------
// 1/(std+eps) from fp64 sums (reciprocal: pos-path only, error-tolerant)
// ---------------------------------------------------------------------------
__global__ void stddev_kernel(const double* __restrict__ sums, float* __restrict__ stdp) {
  const double n = (double)(Bn * Gn * Sn * 3);
  double s1 = sums[0], s2 = sums[1];
  double mean = s1 / n;
  double var = (s2 - s1 * mean) / (n - 1.0);
  float stdf = (float)sqrt(var) + 1e-5f;
  *stdp = (float)(1.0 / (double)stdf);
}

// ===========================================================================
// GEMM family: 128-wide tiles, BK=64, global_load_lds staging (16B/lane),
// XOR seg-swizzle (seg ^= row&7) folded into the SOURCE address so frag
// ds_read_b128 is conflict-free while LDS dest stays lane-contiguous (m104).
// Waves 2x2: wave (wr,wc) computes 64 rows x (64|96) cols via 16x16x32 mfma.
// ===========================================================================

// GEMM1: gathered [neighbor|center] feats (bf16) @ W1^T + b1, ReLU, fused
// Fourier pos-embed epilogue -> G1 bf16. M=131072, N=384, K=384.
__global__ __launch_bounds__(256) void gemm1_kernel(
    const unsigned short* __restrict__ featb, const unsigned short* __restrict__ W1b,
    const float* __restrict__ b1, const int* __restrict__ knn,
    const int* __restrict__ cidx, const float* __restrict__ diffb,
    const float* __restrict__ rstd_p, const float* __restrict__ rdenomTab,
    unsigned short* __restrict__ G1) {
  __shared__ unsigned short As[128 * 64];
  __shared__ unsigned short Bs[128 * 64];
  const int t = threadIdx.x;
  const int bm = blockIdx.x, bn = blockIdx.y;
  const int wid = t >> 6, lane = t & 63, quad = lane >> 4, c16 = lane & 15;
  const int wr = wid >> 1, wc = wid & 1;

  int aOffN[4], aOffC[4], bOff[4];
#pragma unroll
  for (int i = 0; i < 4; ++i) {
    const int slot = i * 256 + t;
    const int row = slot >> 3, segV = slot & 7;
    const int seg = segV ^ (row & 7);
    const int grow = bm * 128 + row;
    const int bg = grow >> 5, s = grow & 31, bb_ = bg >> 9;
    const int nidx = knn[(size_t)bg * Sn + s];
    const int ci = cidx[bg];
    aOffN[i] = (bb_ * Nn + nidx) * Dn + seg * 8;
    aOffC[i] = (bb_ * Nn + ci) * Dn + seg * 8;
    bOff[i] = (bn * 128 + row) * 384 + seg * 8;
  }

  floatx4 acc[4][4];
#pragma unroll
  for (int i = 0; i < 4; ++i)
#pragma unroll
    for (int j = 0; j < 4; ++j) acc[i][j] = (floatx4){0.f, 0.f, 0.f, 0.f};

  for (int kt = 0; kt < 6; ++kt) {
    const int kb = kt * 64;
#pragma unroll
    for (int i = 0; i < 4; ++i) {
      const unsigned short* srcA =
          (kt < 3) ? (featb + aOffN[i] + kb) : (featb + aOffC[i] + (kb - 192));
      gld16(srcA, &As[(i * 256 + wid * 64) * 8]);
      gld16(W1b + bOff[i] + kb, &Bs[(i * 256 + wid * 64) * 8]);
    }
    __syncthreads();
#pragma unroll
    for (int ks = 0; ks < 2; ++ks) {
      ushortx8 af[4], bf[4];
#pragma unroll
      for (int mt = 0; mt < 4; ++mt) {
        const int row = wr * 64 + mt * 16 + c16;
        const int seg = (ks * 4 + quad) ^ (row & 7);
        af[mt] = *(const ushortx8*)&As[row * 64 + seg * 8];
      }
#pragma unroll
      for (int nt = 0; nt < 4; ++nt) {
        const int row = wc * 64 + nt * 16 + c16;
        const int seg = (ks * 4 + quad) ^ (row & 7);
        bf[nt] = *(const ushortx8*)&Bs[row * 64 + seg * 8];
      }
#pragma unroll
      for (int mt = 0; mt < 4; ++mt)
#pragma unroll
        for (int nt = 0; nt < 4; ++nt)
          acc[mt][nt] = mfma_bf16(af[mt], bf[nt], acc[mt][nt]);
    }
    __syncthreads();
  }

  const float rstd = *rstd_p;
  float bias[4], rdnm[4];
  bool usin[4];
#pragma unroll
  for (int nt = 0; nt < 4; ++nt) {
    const int col = bn * 128 + wc * 64 + nt * 16 + c16;
    bias[nt] = b1[col];
    const int j = col & 127;
    usin[nt] = (j < 64);
    rdnm[nt] = rdenomTab[j & 63];
  }
#pragma unroll
  for (int mt = 0; mt < 4; ++mt) {
#pragma unroll
    for (int r = 0; r < 4; ++r) {
      const int row = bm * 128 + wr * 64 + mt * 16 + quad * 4 + r;
      const float dv = diffb[(size_t)row * 3 + bn];     // i3 == bn for 128-col blocks
      const float x = __fmul_rn(dv, rstd);
      const float zb = __fmul_rn(100.0f, x);
#pragma unroll
      for (int nt = 0; nt < 4; ++nt) {
        const int col = bn * 128 + wc * 64 + nt * 16 + c16;
        float y = fmaxf(acc[mt][nt][r] + bias[nt], 0.f);
        float z = __fmul_rn(zb, rdnm[nt]);
        float p = usin[nt] ? __sinf(z) : __cosf(z);
        float g = (y + p) * p;
        G1[(size_t)row * 384 + col] = f2bf(g);
      }
    }
  }
}

// GEMM2: H = relu(G1 @ Wa^T + ba). M=131072, N=192 (one block spans all N),
// K=384. Waves 2x2, wave = 64 rows x 96 cols (acc 4x6).
__global__ __launch_bounds__(256) void gemm2_kernel(
    const unsigned short* __restrict__ G1, const unsigned short* __restrict__ Wab,
    const float* __restrict__ ba, unsigned short* __restrict__ H) {
  __shared__ unsigned short As[128 * 64];
  __shared__ unsigned short Bs[192 * 64];
  const int t = threadIdx.x;
  const int bm = blockIdx.x;
  const int wid = t >> 6, lane = t & 63, quad = lane >> 4, c16 = lane & 15;
  const int wr = wid >> 1, wc = wid & 1;

  int aOff[4], bOff[6];
#pragma unroll
  for (int i = 0; i < 4; ++i) {
    const int slot = i * 256 + t;
    const int row = slot >> 3, segV = slot & 7;
    aOff[i] = (bm * 128 + row) * 384 + (segV ^ (row & 7)) * 8;
  }
#pragma unroll
  for (int i = 0; i < 6; ++i) {
    const int slot = i * 256 + t;
    const int row = slot >> 3, segV = slot & 7;
    bOff[i] = row * 384 + (segV ^ (row & 7)) * 8;
  }

  floatx4 acc[4][6];
#pragma unroll
  for (int i = 0; i < 4; ++i)
#pragma unroll
    for (int j = 0; j < 6; ++j) acc[i][j] = (floatx4){0.f, 0.f, 0.f, 0.f};

  for (int kt = 0; kt < 6; ++kt) {
    const int kb = kt * 64;
#pragma unroll
    for (int i = 0; i < 4; ++i) gld16(G1 + aOff[i] + kb, &As[(i * 256 + wid * 64) * 8]);
#pragma unroll
    for (int i = 0; i < 6; ++i) gld16(Wab + bOff[i] + kb, &Bs[(i * 256 + wid * 64) * 8]);
    __syncthreads();
#pragma unroll
    for (int ks = 0; ks < 2; ++ks) {
      ushortx8 af[4], bf[6];
#pragma unroll
      for (int mt = 0; mt < 4; ++mt) {
        const int row = wr * 64 + mt * 16 + c16;
        const int seg = (ks * 4 + quad) ^ (row & 7);
        af[mt] = *(const ushortx8*)&As[row * 64 + seg * 8];
      }
#pragma unroll
      for (int nt = 0; nt < 6; ++nt) {
        const int row = wc * 96 + nt * 16 + c16;
        const int seg = (ks * 4 + quad) ^ (row & 7);
        bf[nt] = *(const ushortx8*)&Bs[row * 64 + seg * 8];
      }
#pragma unroll
      for (int mt = 0; mt < 4; ++mt)
#pragma unroll
        for (int nt = 0; nt < 6; ++nt)
          acc[mt][nt] = mfma_bf16(af[mt], bf[nt], acc[mt][nt]);
    }
    __syncthreads();
  }

#pragma unroll
  for (int nt = 0; nt < 6; ++nt) {
    const int col = wc * 96 + nt * 16 + c16;
    const float bias = ba[col];
#pragma unroll
    for (int mt = 0; mt < 4; ++mt)
#pragma unroll
      for (int r = 0; r < 4; ++r) {
        const int row = bm * 128 + wr * 64 + mt * 16 + quad * 4 + r;
        H[(size_t)row * 192 + col] = f2bf(fmaxf(acc[mt][nt][r] + bias, 0.f));
      }
  }
}

// GEMM3: relu(H @ Wb^T + bb + G1) + fused max+mean pool over S=32 rows.
// M=131072, N=384, K=192. 128-row tile = 4 groups.
__global__ __launch_bounds__(256) void gemm3_kernel(
    const unsigned short* __restrict__ H, const unsigned short* __restrict__ Wbb,
    const float* __restrict__ bb, const unsigned short* __restrict__ G1,
    float* __restrict__ outp) {
  __shared__ unsigned short As[128 * 64];
  __shared__ unsigned short Bs[128 * 64];
  const int t = threadIdx.x;
  const int bm = blockIdx.x, bn = blockIdx.y;
  const int wid = t >> 6, lane = t & 63, quad = lane >> 4, c16 = lane & 15;
  const int wr = wid >> 1, wc = wid & 1;

  int aOff[4], bOff[4];
#pragma unroll
  for (int i = 0; i < 4; ++i) {
    const int slot = i * 256 + t;
    const int row = slot >> 3, segV = slot & 7;
    const int seg = segV ^ (row & 7);
    aOff[i] = (bm * 128 + row) * 192 + seg * 8;
    bOff[i] = (bn * 128 + row) * 192 + seg * 8;
  }

  floatx4 acc[4][4];
#pragma unroll
  for (int i = 0; i < 4; ++i)
#pragma unroll
    for (int j = 0; j < 4; ++j) acc[i][j] = (floatx4){0.f, 0.f, 0.f, 0.f};

  for (int kt = 0; kt < 3; ++kt) {
    const int kb = kt * 64;
#pragma unroll
    for (int i = 0; i < 4; ++i) {
      gld16(H + aOff[i] + kb, &As[(i * 256 + wid * 64) * 8]);
      gld16(Wbb + bOff[i] + kb, &Bs[(i * 256 + wid * 64) * 8]);
    }
    __syncthreads();
#pragma unroll
    for (int ks = 0; ks < 2; ++ks) {
      ushortx8 af[4], bf[4];
#pragma unroll
      for (int mt = 0; mt < 4; ++mt) {
        const int row = wr * 64 + mt * 16 + c16;
        const int seg = (ks * 4 + quad) ^ (row & 7);
        af[mt] = *(const ushortx8*)&As[row * 64 + seg * 8];
      }
#pragma unroll
      for (int nt = 0; nt < 4; ++nt) {
        const int row = wc * 64 + nt * 16 + c16;
        const int seg = (ks * 4 + quad) ^ (row & 7);
        bf[nt] = *(const ushortx8*)&Bs[row * 64 + seg * 8];
      }
#pragma unroll
      for (int mt = 0; mt < 4; ++mt)
#pragma unroll
        for (int nt = 0; nt < 4; ++nt)
          acc[mt][nt] = mfma_bf16(af[mt], bf[nt], acc[mt][nt]);
    }
    __syncthreads();
  }

#pragma unroll
  for (int nt = 0; nt < 4; ++nt) {
    const int col = bn * 128 + wc * 64 + nt * 16 + c16;
    const float bias = bb[col];
    float gmax[2] = {-INFINITY, -INFINITY};
    float gsum[2] = {0.f, 0.f};
#pragma unroll
    for (int mt = 0; mt < 4; ++mt) {
      const int grp = mt >> 1;
#pragma unroll
      for (int r = 0; r < 4; ++r) {
        const int row = bm * 128 + wr * 64 + mt * 16 + quad * 4 + r;
        float v = acc[mt][nt][r] + bias + bf2f(G1[(size_t)row * 384 + col]);
        v = fmaxf(v, 0.f);
        gmax[grp] = fmaxf(gmax[grp], v);
        gsum[grp] += v;
      }
    }
#pragma unroll
    for (int grp = 0; grp < 2; ++grp) {
      float m = gmax[grp], su = gsum[grp];
#pragma unroll
      for (int off = 16; off <= 32; off <<= 1) {
        m = fmaxf(m, __shfl_xor(m, off, 64));
        su += __shfl_xor(su, off, 64);
      }
      if (quad == 0) {
        const int bg = bm * 4 + wr * 2 + grp;
        outp[(size_t)bg * 384 + col] = m + su / 32.0f;
      }
    }
  }
}

// ---------------------------------------------------------------------------
extern "C" void kernel_launch(void* const* d_in, const int* in_sizes, int n_in,
                              void* d_out, int out_size, void* d_ws, size_t ws_size,
                              hipStream_t stream) {
  const float* points = (const float*)d_in[0];
  const float* feats  = (const float*)d_in[1];
  const float* W1 = (const float*)d_in[2];
  const float* b1 = (const float*)d_in[3];
  const float* Wa = (const float*)d_in[4];
  const float* ba = (const float*)d_in[5];
  const float* Wb = (const float*)d_in[6];
  const float* bb = (const float*)d_in[7];
  float* outF = (float*)d_out;

  char* ws = (char*)d_ws;
  int*            knn      = (int*)(ws + OFF_KNN);
  int*            cidx     = (int*)(ws + OFF_CIDX);
  float*          diffb    = (float*)(ws + OFF_DIFF);
  double*         sums     = (double*)(ws + OFF_SUMS);
  float*          stdp     = (float*)(ws + OFF_STD);
  float*          rdenomTab= (float*)(ws + OFF_DENOM);
  unsigned short* W1b      = (unsigned short*)(ws + OFF_W1B);
  unsigned short* Wab      = (unsigned short*)(ws + OFF_WAB);
  unsigned short* Wbb      = (unsigned short*)(ws + OFF_WBB);
  unsigned short* G1       = (unsigned short*)(ws + OFF_G1);
  unsigned short* H        = (unsigned short*)(ws + OFF_H);
  unsigned short* featb    = (unsigned short*)(ws + OFF_FEATB);   // aliases H

  hipMemsetAsync(sums, 0, 2 * sizeof(double), stream);
  prep_kernel<<<13440, 256, 0, stream>>>(W1, Wa, Wb, feats, W1b, Wab, Wbb, featb, rdenomTab);
  fps_kernel<<<Bn, 256, 0, stream>>>(points, outF);
  knn_kernel<<<Bn * Gn / 4, 256, 0, stream>>>(points, outF, knn, cidx, diffb, sums);
  stddev_kernel<<<1, 1, 0, stream>>>(sums, stdp);
  gemm1_kernel<<<dim3(Mrows / 128, 3), 256, 0, stream>>>(featb, W1b, b1, knn, cidx,
                                                         diffb, stdp, rdenomTab, G1);
  gemm2_kernel<<<Mrows / 128, 256, 0, stream>>>(G1, Wab, ba, H);
  gemm3_kernel<<<dim3(Mrows / 128, 3), 256, 0, stream>>>(H, Wbb, bb, G1, outF + Bn * Gn * 3);
}